// Round 1
// baseline (1060.037 us; speedup 1.0000x reference)
//
#include <hip/hip_runtime.h>
#include <hip/hip_bf16.h>
#include <cstddef>

#define NN 50000
#define EE 1600000
#define GG 512

// ---------------- CSR build ----------------

__global__ void hist_kernel(const int* __restrict__ ei, int* __restrict__ cnt) {
    int e = blockIdx.x * 256 + threadIdx.x;
    if (e < EE) atomicAdd(&cnt[ei[EE + e]], 1);
}

__global__ __launch_bounds__(1024) void scan_kernel(int* __restrict__ cur, int* __restrict__ ofs) {
    // exclusive prefix over cur[0..NN) -> ofs; also re-init cur to row starts (cursors)
    __shared__ int sums[1024];
    const int n = NN;
    int t = threadIdx.x;
    int seg = (n + 1023) >> 10;            // 49
    int beg = t * seg;
    int end = beg + seg; if (end > n) end = n;
    int s = 0;
    for (int i = beg; i < end; ++i) s += cur[i];
    sums[t] = s;
    __syncthreads();
    for (int off = 1; off < 1024; off <<= 1) {
        int v = (t >= off) ? sums[t - off] : 0;
        __syncthreads();
        sums[t] += v;
        __syncthreads();
    }
    int run = sums[t] - s;                 // exclusive prefix of this segment
    for (int i = beg; i < end; ++i) {
        int c = cur[i];
        ofs[i] = run;
        cur[i] = run;
        run += c;
    }
    if (t == 1023) ofs[n] = sums[1023];
}

__global__ void fill_kernel(const int* __restrict__ ei, int* __restrict__ cur,
                            int* __restrict__ srcl) {
    int e = blockIdx.x * 256 + threadIdx.x;
    if (e < EE) {
        int dst = ei[EE + e];
        int p = atomicAdd(&cur[dst], 1);
        srcl[p] = ei[e];
    }
}

// ---------------- pull aggregation (one wave per node, 128 channels) ----------------

__global__ __launch_bounds__(256) void pull_kernel(const float* __restrict__ X, int ldx,
                                                   const int* __restrict__ ofs,
                                                   const int* __restrict__ srcl,
                                                   float* __restrict__ out) {
    int node = (blockIdx.x * 256 + threadIdx.x) >> 6;
    int lane = threadIdx.x & 63;
    if (node >= NN) return;
    int lo = ofs[node], hi = ofs[node + 1];
    int c = lane * 2;
    float ax = 0.f, ay = 0.f;
    int j = lo;
    for (; j + 1 < hi; j += 2) {
        int s0 = srcl[j], s1 = srcl[j + 1];
        float2 v0 = *(const float2*)(X + (size_t)s0 * ldx + c);
        float2 v1 = *(const float2*)(X + (size_t)s1 * ldx + c);
        ax += v0.x + v1.x;
        ay += v0.y + v1.y;
    }
    if (j < hi) {
        int s0 = srcl[j];
        float2 v0 = *(const float2*)(X + (size_t)s0 * ldx + c);
        ax += v0.x;
        ay += v0.y;
    }
    float2 r; r.x = ax; r.y = ay;
    *(float2*)(out + (size_t)node * 128 + c) = r;
}

// ---------------- fused fp32 GEMM: C = A1@B1 (+ A2@B2) (+bias) (ReLU) ----------------
// A row-major [N,K], B row-major [K,M]. Tile: 128 rows x 64 cols, 256 threads, 8x4/thread.

__global__ __launch_bounds__(256) void gemm_kernel(
    const float* __restrict__ A1, const float* __restrict__ B1, int K1,
    const float* __restrict__ A2, const float* __restrict__ B2, int K2,
    const float* __restrict__ bias, float* __restrict__ C,
    int ldc, int coloff, int M, int relu) {
    __shared__ float As[128][16];
    __shared__ float Bs[16][64];
    const int t = threadIdx.x;
    const int tx = t & 15, ty = t >> 4;
    const int row0 = blockIdx.y * 128;
    const int c0 = blockIdx.x * 64;

    float acc[8][4];
#pragma unroll
    for (int r = 0; r < 8; ++r)
#pragma unroll
        for (int c = 0; c < 4; ++c) acc[r][c] = 0.f;

    for (int pass = 0; pass < 2; ++pass) {
        const float* A = pass ? A2 : A1;
        const float* B = pass ? B2 : B1;
        const int K = pass ? K2 : K1;
        if (!A) continue;
        for (int kk = 0; kk < K; kk += 16) {
            __syncthreads();
            // stage A: 128 rows x 16 k
#pragma unroll
            for (int i = 0; i < 2; ++i) {
                int idx = t + i * 256;
                int row = idx >> 2, kq = idx & 3;
                int grow = row0 + row;
                if (grow > NN - 1) grow = NN - 1;
                float4 v = *(const float4*)(A + (size_t)grow * K + kk + kq * 4);
                *(float4*)&As[row][kq * 4] = v;
            }
            // stage B: 16 k x 64 cols
            {
                int kb = t >> 4, cb = (t & 15) * 4;
                float4 v = *(const float4*)(B + (size_t)(kk + kb) * M + c0 + cb);
                *(float4*)&Bs[kb][cb] = v;
            }
            __syncthreads();
#pragma unroll
            for (int k = 0; k < 16; ++k) {
                float4 bv = *(const float4*)&Bs[k][tx * 4];
#pragma unroll
                for (int r = 0; r < 8; ++r) {
                    float a = As[ty * 8 + r][k];
                    acc[r][0] += a * bv.x;
                    acc[r][1] += a * bv.y;
                    acc[r][2] += a * bv.z;
                    acc[r][3] += a * bv.w;
                }
            }
        }
    }
#pragma unroll
    for (int r = 0; r < 8; ++r) {
        int grow = row0 + ty * 8 + r;
        if (grow < NN) {
            float4 v;
            float x0 = acc[r][0], x1 = acc[r][1], x2 = acc[r][2], x3 = acc[r][3];
            if (bias) {
                const float* bp = bias + c0 + tx * 4;
                x0 += bp[0]; x1 += bp[1]; x2 += bp[2]; x3 += bp[3];
            }
            if (relu) {
                x0 = fmaxf(x0, 0.f); x1 = fmaxf(x1, 0.f);
                x2 = fmaxf(x2, 0.f); x3 = fmaxf(x3, 0.f);
            }
            v.x = x0; v.y = x1; v.z = x2; v.w = x3;
            *(float4*)(C + (size_t)grow * ldc + coloff + c0 + tx * 4) = v;
        }
    }
}

// ---------------- h3 = agg3 + o3 (elementwise) ----------------

__global__ void add_o3_kernel(float* __restrict__ agg, const float* __restrict__ t3o3) {
    int idx = blockIdx.x * 256 + threadIdx.x;
    if (idx < NN * 128) {
        int row = idx >> 7, c = idx & 127;
        agg[idx] += t3o3[(size_t)row * 256 + 128 + c];
    }
}

// ---------------- mean pool over sorted batch ----------------

__device__ inline int lower_bound_i(const int* a, int n, int v) {
    int lo = 0, hi = n;
    while (lo < hi) {
        int m = (lo + hi) >> 1;
        if (a[m] < v) lo = m + 1; else hi = m;
    }
    return lo;
}

__global__ __launch_bounds__(128) void pool_kernel(const float* __restrict__ h,
                                                   const int* __restrict__ batch,
                                                   float* __restrict__ pooled) {
    int g = blockIdx.x, c = threadIdx.x;
    int lo = lower_bound_i(batch, NN, g);
    int hi = lower_bound_i(batch, NN, g + 1);
    float s = 0.f;
    for (int i = lo; i < hi; ++i) s += h[(size_t)i * 128 + c];
    pooled[g * 128 + c] = s / fmaxf((float)(hi - lo), 1.f);
}

// ---------------- head: out = (pooled @ W1 + b1) @ W2 + b2 ----------------

__global__ __launch_bounds__(64) void head_kernel(const float* __restrict__ pooled,
                                                  const float* __restrict__ W1,
                                                  const float* __restrict__ b1,
                                                  const float* __restrict__ W2,
                                                  const float* __restrict__ b2,
                                                  float* __restrict__ out) {
    __shared__ float p[128];
    __shared__ float hid[40];
    int g = blockIdx.x, t = threadIdx.x;
    p[t] = pooled[g * 128 + t];
    p[t + 64] = pooled[g * 128 + 64 + t];
    __syncthreads();
    if (t < 40) {
        float s = b1[t];
        for (int k = 0; k < 128; ++k) s += p[k] * W1[k * 40 + t];
        hid[t] = s;
    }
    __syncthreads();
    if (t < 10) {
        float s = b2[t];
        for (int j = 0; j < 40; ++j) s += hid[j] * W2[j * 10 + t];
        out[g * 10 + t] = s;
    }
}

// ---------------- launch ----------------

extern "C" void kernel_launch(void* const* d_in, const int* in_sizes, int n_in,
                              void* d_out, int out_size, void* d_ws, size_t ws_size,
                              hipStream_t stream) {
    const float* x   = (const float*)d_in[0];
    const int* ei    = (const int*)d_in[1];   // [2, E]: row0=src, row1=dst
    const int* batch = (const int*)d_in[2];
    const float* Wr1 = (const float*)d_in[3];
    const float* br1 = (const float*)d_in[4];
    const float* Wo1 = (const float*)d_in[5];
    const float* Wr2 = (const float*)d_in[6];
    const float* br2 = (const float*)d_in[7];
    const float* Wo2 = (const float*)d_in[8];
    const float* Wr3 = (const float*)d_in[9];
    const float* br3 = (const float*)d_in[10];
    const float* Wo3 = (const float*)d_in[11];
    const float* W1  = (const float*)d_in[12];
    const float* b1  = (const float*)d_in[13];
    const float* W2  = (const float*)d_in[14];
    const float* b2  = (const float*)d_in[15];
    float* out = (float*)d_out;

    char* ws = (char*)d_ws;
    size_t off = 0;
    auto alloc = [&](size_t bytes) {
        void* p = ws + off;
        off += (bytes + 255) & ~(size_t)255;
        return p;
    };
    int* ofs     = (int*)alloc((NN + 1) * sizeof(int));
    int* cur     = (int*)alloc(NN * sizeof(int));
    int* srcl    = (int*)alloc((size_t)EE * sizeof(int));
    float* agg   = (float*)alloc((size_t)NN * 128 * sizeof(float));  // agg1/agg2/agg3 (+h3 in place)
    float* h1    = (float*)alloc((size_t)NN * 128 * sizeof(float));
    float* h2    = (float*)alloc((size_t)NN * 256 * sizeof(float));
    float* t3o3  = (float*)alloc((size_t)NN * 256 * sizeof(float));  // cols 0..127 = t3, 128..255 = o3
    float* pooled = (float*)alloc((size_t)GG * 128 * sizeof(float));

    // CSR by dst (rebuilt every call; ws is re-poisoned between calls)
    hipMemsetAsync(cur, 0, NN * sizeof(int), stream);
    hist_kernel<<<EE / 256, 256, 0, stream>>>(ei, cur);
    scan_kernel<<<1, 1024, 0, stream>>>(cur, ofs);
    fill_kernel<<<EE / 256, 256, 0, stream>>>(ei, cur, srcl);

    // conv1: h1 = relu(agg(x)@Wr1 + x@Wo1 + br1)
    pull_kernel<<<(NN * 64) / 256, 256, 0, stream>>>(x, 128, ofs, srcl, agg);
    gemm_kernel<<<dim3(2, 391), 256, 0, stream>>>(agg, Wr1, 128, x, Wo1, 128, br1,
                                                  h1, 128, 0, 128, 1);
    // conv2: h2 = relu(agg(h1)@Wr2 + h1@Wo2 + br2)
    pull_kernel<<<(NN * 64) / 256, 256, 0, stream>>>(h1, 128, ofs, srcl, agg);
    gemm_kernel<<<dim3(4, 391), 256, 0, stream>>>(agg, Wr2, 128, h1, Wo2, 128, br2,
                                                  h2, 256, 0, 256, 1);
    // conv3 (transform-then-aggregate): t3 = h2@Wr3 ; o3 = h2@Wo3 + br3
    gemm_kernel<<<dim3(2, 391), 256, 0, stream>>>(h2, Wr3, 256, nullptr, nullptr, 0, nullptr,
                                                  t3o3, 256, 0, 128, 0);
    gemm_kernel<<<dim3(2, 391), 256, 0, stream>>>(h2, Wo3, 256, nullptr, nullptr, 0, br3,
                                                  t3o3, 256, 128, 128, 0);
    // h3 = agg(t3) + o3   (into agg, in place)
    pull_kernel<<<(NN * 64) / 256, 256, 0, stream>>>(t3o3, 256, ofs, srcl, agg);
    add_o3_kernel<<<(NN * 128) / 256, 256, 0, stream>>>(agg, t3o3);

    // mean pool (batch sorted -> contiguous ranges) + head
    pool_kernel<<<GG, 128, 0, stream>>>(agg, batch, pooled);
    head_kernel<<<GG, 64, 0, stream>>>(pooled, W1, b1, W2, b2, out);
}

// Round 2
// 931.334 us; speedup vs baseline: 1.1382x; 1.1382x over previous
//
#include <hip/hip_runtime.h>
#include <hip/hip_bf16.h>
#include <cstddef>

#define NN 50000
#define EE 1600000
#define GG 512
#define NB 196        // ceil(NN/256) buckets for the scatter fix
#define BCAP 10240    // LDS staging capacity per bucket (avg span 8192, max ~8600)

// ---------------- CSR build ----------------

__global__ void hist_kernel(const int* __restrict__ ei, int* __restrict__ cnt) {
    int e = blockIdx.x * 256 + threadIdx.x;
    if (e < EE) atomicAdd(&cnt[ei[EE + e]], 1);
}

__global__ __launch_bounds__(1024) void scan_kernel(int* __restrict__ cur, int* __restrict__ ofs) {
    // exclusive prefix over cur[0..NN) -> ofs
    __shared__ int sums[1024];
    const int n = NN;
    int t = threadIdx.x;
    int seg = (n + 1023) >> 10;            // 49
    int beg = t * seg;
    int end = beg + seg; if (end > n) end = n;
    int s = 0;
    for (int i = beg; i < end; ++i) s += cur[i];
    sums[t] = s;
    __syncthreads();
    for (int off = 1; off < 1024; off <<= 1) {
        int v = (t >= off) ? sums[t - off] : 0;
        __syncthreads();
        sums[t] += v;
        __syncthreads();
    }
    int run = sums[t] - s;                 // exclusive prefix of this segment
    for (int i = beg; i < end; ++i) {
        int c = cur[i];
        ofs[i] = run;
        run += c;
    }
    if (t == 1023) ofs[n] = sums[1023];
}

__global__ void bucket_init_kernel(const int* __restrict__ ofs, int* __restrict__ bcur) {
    int b = threadIdx.x;
    if (b < NB) bcur[b] = ofs[b << 8];   // bucket b's region in pairs[] = CSR span of its nodes
}

// Pass 1: bin edges by dst>>8. Per-block LDS histogram + rank, one global atomic
// per (bucket, block) to reserve a contiguous run -> coalesced-ish writes.
__global__ __launch_bounds__(256) void bscatter_kernel(const int* __restrict__ ei,
                                                       int* __restrict__ bcur,
                                                       unsigned int* __restrict__ pairs) {
    __shared__ int lcnt[NB];
    __shared__ int lbase[NB];
    __shared__ unsigned short lpos[4096];
    int t = threadIdx.x;
    int e0 = blockIdx.x * 4096;
    for (int i = t; i < NB; i += 256) lcnt[i] = 0;
    __syncthreads();
#pragma unroll
    for (int i = 0; i < 16; ++i) {
        int e = e0 + i * 256 + t;
        if (e < EE) {
            int b = ei[EE + e] >> 8;
            lpos[i * 256 + t] = (unsigned short)atomicAdd(&lcnt[b], 1);
        }
    }
    __syncthreads();
    for (int i = t; i < NB; i += 256) lbase[i] = atomicAdd(&bcur[i], lcnt[i]);
    __syncthreads();
#pragma unroll
    for (int i = 0; i < 16; ++i) {
        int e = e0 + i * 256 + t;
        if (e < EE) {
            int src = ei[e], dst = ei[EE + e];
            int b = dst >> 8;
            int pos = lbase[b] + (int)lpos[i * 256 + t];
            pairs[pos] = ((unsigned)src << 8) | (unsigned)(dst & 255);
        }
    }
}

// Pass 2: one block per bucket; scatter within LDS (node span ~32KB), write srcl sequentially.
__global__ __launch_bounds__(256) void bfill_kernel(const int* __restrict__ ofs,
                                                    const unsigned int* __restrict__ pairs,
                                                    int* __restrict__ srcl) {
    __shared__ int lcur[256];
    __shared__ int lbuf[BCAP];
    int b = blockIdx.x, t = threadIdx.x;
    int n0 = b << 8;
    int ncnt = NN - n0; if (ncnt > 256) ncnt = 256;
    int base = ofs[n0];
    int limit = ofs[n0 + ncnt];
    if (t < ncnt) lcur[t] = ofs[n0 + t] - base;
    __syncthreads();
    int span = limit - base;
    for (int j = t; j < span; j += 256) {
        unsigned int p = pairs[base + j];
        int pos = atomicAdd(&lcur[p & 255u], 1);
        int src = (int)(p >> 8);
        if (pos < BCAP) lbuf[pos] = src;
        else srcl[base + pos] = src;     // overflow fallback (statistically never)
    }
    __syncthreads();
    int lim = span < BCAP ? span : BCAP;
    for (int j = t; j < lim; j += 256) srcl[base + j] = lbuf[j];
}

// ---------------- pull aggregation (one wave per node, 128 channels) ----------------

__global__ __launch_bounds__(256) void pull_kernel(const float* __restrict__ X, int ldx,
                                                   const int* __restrict__ ofs,
                                                   const int* __restrict__ srcl,
                                                   float* __restrict__ out) {
    int node = (blockIdx.x * 256 + threadIdx.x) >> 6;
    int lane = threadIdx.x & 63;
    if (node >= NN) return;
    int lo = ofs[node], hi = ofs[node + 1];
    int c = lane * 2;
    float ax = 0.f, ay = 0.f;
    int j = lo;
    for (; j + 1 < hi; j += 2) {
        int s0 = srcl[j], s1 = srcl[j + 1];
        float2 v0 = *(const float2*)(X + (size_t)s0 * ldx + c);
        float2 v1 = *(const float2*)(X + (size_t)s1 * ldx + c);
        ax += v0.x + v1.x;
        ay += v0.y + v1.y;
    }
    if (j < hi) {
        int s0 = srcl[j];
        float2 v0 = *(const float2*)(X + (size_t)s0 * ldx + c);
        ax += v0.x;
        ay += v0.y;
    }
    float2 r; r.x = ax; r.y = ay;
    *(float2*)(out + (size_t)node * 128 + c) = r;
}

// ---------------- fused fp32 GEMM: C = A1@B1 (+ A2@B2) (+bias) (ReLU) ----------------
// A row-major [N,K], B row-major [K,M]. Tile: 128 rows x 128 cols, 256 threads,
// 8x8 per thread split as (4+4)x(4+4) so LDS reads are 2-way aliased (free per m136).

__global__ __launch_bounds__(256, 2) void gemm_kernel(
    const float* __restrict__ A1, const float* __restrict__ B1, int K1,
    const float* __restrict__ A2, const float* __restrict__ B2, int K2,
    const float* __restrict__ bias, float* __restrict__ C,
    int ldc, int coloff, int M, int relu) {
    __shared__ float As[16][132];   // [k][row], +4 pad breaks write conflicts
    __shared__ float Bs[16][132];   // [k][col]
    const int t = threadIdx.x;
    const int tx = t & 15, ty = t >> 4;
    const int row0 = blockIdx.y * 128;
    const int c0 = blockIdx.x * 128;

    float acc[2][2][4][4];
#pragma unroll
    for (int rh = 0; rh < 2; ++rh)
#pragma unroll
        for (int ch = 0; ch < 2; ++ch)
#pragma unroll
            for (int r = 0; r < 4; ++r)
#pragma unroll
                for (int c = 0; c < 4; ++c) acc[rh][ch][r][c] = 0.f;

    for (int pass = 0; pass < 2; ++pass) {
        const float* A = pass ? A2 : A1;
        const float* B = pass ? B2 : B1;
        const int K = pass ? K2 : K1;
        if (!A) continue;
        for (int kk = 0; kk < K; kk += 16) {
            __syncthreads();
            // stage A: 128 rows x 16 k (transposed into [k][row])
#pragma unroll
            for (int i = 0; i < 2; ++i) {
                int idx = t + i * 256;
                int row = idx >> 2, q = idx & 3;
                int grow = row0 + row;
                if (grow >= NN) grow = NN - 1;
                float4 v = *(const float4*)(A + (size_t)grow * K + kk + q * 4);
                As[q * 4 + 0][row] = v.x;
                As[q * 4 + 1][row] = v.y;
                As[q * 4 + 2][row] = v.z;
                As[q * 4 + 3][row] = v.w;
            }
            // stage B: 16 k x 128 cols
#pragma unroll
            for (int i = 0; i < 2; ++i) {
                int idx = t + i * 256;
                int kb = idx >> 5, cb = (idx & 31) * 4;
                float4 v = *(const float4*)(B + (size_t)(kk + kb) * M + c0 + cb);
                *(float4*)&Bs[kb][cb] = v;
            }
            __syncthreads();
#pragma unroll
            for (int k = 0; k < 16; ++k) {
                float4 a0 = *(const float4*)&As[k][ty * 4];
                float4 a1 = *(const float4*)&As[k][64 + ty * 4];
                float4 b0 = *(const float4*)&Bs[k][tx * 4];
                float4 b1 = *(const float4*)&Bs[k][64 + tx * 4];
                float ar[2][4] = {{a0.x, a0.y, a0.z, a0.w}, {a1.x, a1.y, a1.z, a1.w}};
                float bc[2][4] = {{b0.x, b0.y, b0.z, b0.w}, {b1.x, b1.y, b1.z, b1.w}};
#pragma unroll
                for (int rh = 0; rh < 2; ++rh)
#pragma unroll
                    for (int r = 0; r < 4; ++r)
#pragma unroll
                        for (int ch = 0; ch < 2; ++ch)
#pragma unroll
                            for (int c = 0; c < 4; ++c)
                                acc[rh][ch][r][c] += ar[rh][r] * bc[ch][c];
            }
        }
    }
#pragma unroll
    for (int rh = 0; rh < 2; ++rh)
#pragma unroll
        for (int r = 0; r < 4; ++r) {
            int grow = row0 + rh * 64 + ty * 4 + r;
            if (grow >= NN) continue;
#pragma unroll
            for (int ch = 0; ch < 2; ++ch) {
                float x0 = acc[rh][ch][r][0], x1 = acc[rh][ch][r][1];
                float x2 = acc[rh][ch][r][2], x3 = acc[rh][ch][r][3];
                if (bias) {
                    const float* bp = bias + c0 + ch * 64 + tx * 4;
                    x0 += bp[0]; x1 += bp[1]; x2 += bp[2]; x3 += bp[3];
                }
                if (relu) {
                    x0 = fmaxf(x0, 0.f); x1 = fmaxf(x1, 0.f);
                    x2 = fmaxf(x2, 0.f); x3 = fmaxf(x3, 0.f);
                }
                float4 v; v.x = x0; v.y = x1; v.z = x2; v.w = x3;
                *(float4*)(C + (size_t)grow * ldc + coloff + c0 + ch * 64 + tx * 4) = v;
            }
        }
}

// ---------------- h3 = agg3 + o3 (elementwise) ----------------

__global__ void add_o3_kernel(float* __restrict__ agg, const float* __restrict__ t3o3) {
    int idx = blockIdx.x * 256 + threadIdx.x;
    if (idx < NN * 128) {
        int row = idx >> 7, c = idx & 127;
        agg[idx] += t3o3[(size_t)row * 256 + 128 + c];
    }
}

// ---------------- mean pool over sorted batch ----------------

__device__ inline int lower_bound_i(const int* a, int n, int v) {
    int lo = 0, hi = n;
    while (lo < hi) {
        int m = (lo + hi) >> 1;
        if (a[m] < v) lo = m + 1; else hi = m;
    }
    return lo;
}

__global__ __launch_bounds__(128) void pool_kernel(const float* __restrict__ h,
                                                   const int* __restrict__ batch,
                                                   float* __restrict__ pooled) {
    int g = blockIdx.x, c = threadIdx.x;
    int lo = lower_bound_i(batch, NN, g);
    int hi = lower_bound_i(batch, NN, g + 1);
    float s = 0.f;
    for (int i = lo; i < hi; ++i) s += h[(size_t)i * 128 + c];
    pooled[g * 128 + c] = s / fmaxf((float)(hi - lo), 1.f);
}

// ---------------- head: out = (pooled @ W1 + b1) @ W2 + b2 ----------------

__global__ __launch_bounds__(64) void head_kernel(const float* __restrict__ pooled,
                                                  const float* __restrict__ W1,
                                                  const float* __restrict__ b1,
                                                  const float* __restrict__ W2,
                                                  const float* __restrict__ b2,
                                                  float* __restrict__ out) {
    __shared__ float p[128];
    __shared__ float hid[40];
    int g = blockIdx.x, t = threadIdx.x;
    p[t] = pooled[g * 128 + t];
    p[t + 64] = pooled[g * 128 + 64 + t];
    __syncthreads();
    if (t < 40) {
        float s = b1[t];
        for (int k = 0; k < 128; ++k) s += p[k] * W1[k * 40 + t];
        hid[t] = s;
    }
    __syncthreads();
    if (t < 10) {
        float s = b2[t];
        for (int j = 0; j < 40; ++j) s += hid[j] * W2[j * 10 + t];
        out[g * 10 + t] = s;
    }
}

// ---------------- launch ----------------

extern "C" void kernel_launch(void* const* d_in, const int* in_sizes, int n_in,
                              void* d_out, int out_size, void* d_ws, size_t ws_size,
                              hipStream_t stream) {
    const float* x   = (const float*)d_in[0];
    const int* ei    = (const int*)d_in[1];   // [2, E]: row0=src, row1=dst
    const int* batch = (const int*)d_in[2];
    const float* Wr1 = (const float*)d_in[3];
    const float* br1 = (const float*)d_in[4];
    const float* Wo1 = (const float*)d_in[5];
    const float* Wr2 = (const float*)d_in[6];
    const float* br2 = (const float*)d_in[7];
    const float* Wo2 = (const float*)d_in[8];
    const float* Wr3 = (const float*)d_in[9];
    const float* br3 = (const float*)d_in[10];
    const float* Wo3 = (const float*)d_in[11];
    const float* W1  = (const float*)d_in[12];
    const float* b1  = (const float*)d_in[13];
    const float* W2  = (const float*)d_in[14];
    const float* b2  = (const float*)d_in[15];
    float* out = (float*)d_out;

    char* ws = (char*)d_ws;
    size_t off = 0;
    auto alloc = [&](size_t bytes) {
        void* p = ws + off;
        off += (bytes + 255) & ~(size_t)255;
        return p;
    };
    int* ofs     = (int*)alloc((NN + 1) * sizeof(int));
    int* cur     = (int*)alloc(NN * sizeof(int));
    int* bcur    = (int*)alloc(256 * sizeof(int));
    int* srcl    = (int*)alloc((size_t)EE * sizeof(int));
    float* agg   = (float*)alloc((size_t)NN * 128 * sizeof(float));  // agg1/agg2/agg3 (+h3 in place)
    float* h1    = (float*)alloc((size_t)NN * 128 * sizeof(float));
    float* h2    = (float*)alloc((size_t)NN * 256 * sizeof(float));
    float* t3o3  = (float*)alloc((size_t)NN * 256 * sizeof(float));  // cols 0..127=t3, 128..255=o3
    float* pooled = (float*)alloc((size_t)GG * 128 * sizeof(float));
    // pairs[] lifetime (CSR build) is disjoint from t3o3 (conv3) -> overlay, no extra ws
    unsigned int* pairs = (unsigned int*)t3o3;

    // CSR by dst (rebuilt every call; ws is re-poisoned between calls)
    hipMemsetAsync(cur, 0, NN * sizeof(int), stream);
    hist_kernel<<<EE / 256, 256, 0, stream>>>(ei, cur);
    scan_kernel<<<1, 1024, 0, stream>>>(cur, ofs);
    bucket_init_kernel<<<1, 256, 0, stream>>>(ofs, bcur);
    bscatter_kernel<<<(EE + 4095) / 4096, 256, 0, stream>>>(ei, bcur, pairs);
    bfill_kernel<<<NB, 256, 0, stream>>>(ofs, pairs, srcl);

    // conv1: h1 = relu(agg(x)@Wr1 + x@Wo1 + br1)
    pull_kernel<<<(NN * 64) / 256, 256, 0, stream>>>(x, 128, ofs, srcl, agg);
    gemm_kernel<<<dim3(1, 391), 256, 0, stream>>>(agg, Wr1, 128, x, Wo1, 128, br1,
                                                  h1, 128, 0, 128, 1);
    // conv2: h2 = relu(agg(h1)@Wr2 + h1@Wo2 + br2)
    pull_kernel<<<(NN * 64) / 256, 256, 0, stream>>>(h1, 128, ofs, srcl, agg);
    gemm_kernel<<<dim3(2, 391), 256, 0, stream>>>(agg, Wr2, 128, h1, Wo2, 128, br2,
                                                  h2, 256, 0, 256, 1);
    // conv3 (transform-then-aggregate): t3 = h2@Wr3 ; o3 = h2@Wo3 + br3
    gemm_kernel<<<dim3(1, 391), 256, 0, stream>>>(h2, Wr3, 256, nullptr, nullptr, 0, nullptr,
                                                  t3o3, 256, 0, 128, 0);
    gemm_kernel<<<dim3(1, 391), 256, 0, stream>>>(h2, Wo3, 256, nullptr, nullptr, 0, br3,
                                                  t3o3, 256, 128, 128, 0);
    // h3 = agg(t3) + o3   (into agg, in place)
    pull_kernel<<<(NN * 64) / 256, 256, 0, stream>>>(t3o3, 256, ofs, srcl, agg);
    add_o3_kernel<<<(NN * 128) / 256, 256, 0, stream>>>(agg, t3o3);

    // mean pool (batch sorted -> contiguous ranges) + head
    pool_kernel<<<GG, 128, 0, stream>>>(agg, batch, pooled);
    head_kernel<<<GG, 64, 0, stream>>>(pooled, W1, b1, W2, b2, out);
}

// Round 3
// 577.308 us; speedup vs baseline: 1.8362x; 1.6132x over previous
//
#include <hip/hip_runtime.h>
#include <hip/hip_bf16.h>
#include <cstddef>

#define NN 50000
#define EE 1600000
#define GG 512
#define NB 196        // ceil(NN/256) buckets
#define BCAP 10240    // LDS staging per bucket

typedef unsigned int u32;
typedef unsigned short u16;
typedef __attribute__((ext_vector_type(8))) short frag_ab;   // 8 bf16 = 4 VGPRs
typedef __attribute__((ext_vector_type(4))) float frag_cd;   // 4 fp32 acc

__device__ __forceinline__ void gl_lds16(const void* g, void* l) {
    __builtin_amdgcn_global_load_lds(
        (const __attribute__((address_space(1))) u32*)g,
        (__attribute__((address_space(3))) u32*)l, 16, 0, 0);
}
__device__ __forceinline__ float b2f_lo(u32 v) { return __uint_as_float(v << 16); }
__device__ __forceinline__ float b2f_hi(u32 v) { return __uint_as_float(v & 0xffff0000u); }
__device__ __forceinline__ u16 f2b(float x) {
    __hip_bfloat16 h = __float2bfloat16(x);
    return *(u16*)&h;
}

// ---------------- CSR build ----------------

__global__ void hist_kernel(const int* __restrict__ ei, int* __restrict__ cnt) {
    int e = blockIdx.x * 256 + threadIdx.x;
    if (e < EE) atomicAdd(&cnt[ei[EE + e]], 1);
}

__global__ __launch_bounds__(1024) void scan_kernel(const int* __restrict__ cnt,
                                                    int* __restrict__ ofs) {
    __shared__ int sums[1024];
    const int n = NN;
    int t = threadIdx.x;
    int seg = (n + 1023) >> 10;
    int beg = t * seg;
    int end = beg + seg; if (end > n) end = n;
    int s = 0;
    for (int i = beg; i < end; ++i) s += cnt[i];
    sums[t] = s;
    __syncthreads();
    for (int off = 1; off < 1024; off <<= 1) {
        int v = (t >= off) ? sums[t - off] : 0;
        __syncthreads();
        sums[t] += v;
        __syncthreads();
    }
    int run = sums[t] - s;
    for (int i = beg; i < end; ++i) {
        int c = cnt[i];
        ofs[i] = run;
        run += c;
    }
    if (t == 1023) ofs[n] = sums[1023];
}

__global__ void bucket_init_kernel(const int* __restrict__ ofs, int* __restrict__ bcur) {
    int b = threadIdx.x;
    if (b < NB) bcur[b] = ofs[b << 8];
}

__global__ __launch_bounds__(256) void bscatter_kernel(const int* __restrict__ ei,
                                                       int* __restrict__ bcur,
                                                       u32* __restrict__ pairs) {
    __shared__ int lcnt[NB];
    __shared__ int lbase[NB];
    __shared__ unsigned short lpos[4096];
    int t = threadIdx.x;
    int e0 = blockIdx.x * 4096;
    for (int i = t; i < NB; i += 256) lcnt[i] = 0;
    __syncthreads();
#pragma unroll
    for (int i = 0; i < 16; ++i) {
        int e = e0 + i * 256 + t;
        if (e < EE) {
            int b = ei[EE + e] >> 8;
            lpos[i * 256 + t] = (unsigned short)atomicAdd(&lcnt[b], 1);
        }
    }
    __syncthreads();
    for (int i = t; i < NB; i += 256) lbase[i] = atomicAdd(&bcur[i], lcnt[i]);
    __syncthreads();
#pragma unroll
    for (int i = 0; i < 16; ++i) {
        int e = e0 + i * 256 + t;
        if (e < EE) {
            int src = ei[e], dst = ei[EE + e];
            int b = dst >> 8;
            int pos = lbase[b] + (int)lpos[i * 256 + t];
            pairs[pos] = ((u32)src << 8) | (u32)(dst & 255);
        }
    }
}

__global__ __launch_bounds__(256) void bfill_kernel(const int* __restrict__ ofs,
                                                    const u32* __restrict__ pairs,
                                                    int* __restrict__ srcl) {
    __shared__ int lcur[256];
    __shared__ int lbuf[BCAP];
    int b = blockIdx.x, t = threadIdx.x;
    int n0 = b << 8;
    int ncnt = NN - n0; if (ncnt > 256) ncnt = 256;
    int base = ofs[n0];
    int limit = ofs[n0 + ncnt];
    if (t < ncnt) lcur[t] = ofs[n0 + t] - base;
    __syncthreads();
    int span = limit - base;
    for (int j = t; j < span; j += 256) {
        u32 p = pairs[base + j];
        int pos = atomicAdd(&lcur[p & 255u], 1);
        int src = (int)(p >> 8);
        if (pos < BCAP) lbuf[pos] = src;
        else srcl[base + pos] = src;
    }
    __syncthreads();
    int lim = span < BCAP ? span : BCAP;
    for (int j = t; j < lim; j += 256) srcl[base + j] = lbuf[j];
}

// ---------------- weight prep: BT[M][256] bf16 (pre-transposed concat) ----------------

__global__ __launch_bounds__(256) void prep_w_kernel(
    const float* __restrict__ Wr1, const float* __restrict__ Wo1,
    const float* __restrict__ Wr2, const float* __restrict__ Wo2,
    const float* __restrict__ Wr3, const float* __restrict__ Wo3,
    const float* __restrict__ br3,
    u16* __restrict__ BT1, u16* __restrict__ BT2, u16* __restrict__ BT3,
    float* __restrict__ bias3) {
    int m = blockIdx.x;          // 0..255 (output col)
    int k = threadIdx.x;         // 0..255 (reduction idx)
    // BT2: [Wr2;Wo2], Wr2/Wo2 are [128][256]
    BT2[m * 256 + k] = f2b(k < 128 ? Wr2[k * 256 + m] : Wo2[(k - 128) * 256 + m]);
    // BT3: [Wr3|Wo3], Wr3/Wo3 are [256][128]
    BT3[m * 256 + k] = f2b(m < 128 ? Wr3[k * 128 + m] : Wo3[k * 128 + (m - 128)]);
    // BT1: [Wr1;Wo1], [128][128] each; only m<128
    if (m < 128)
        BT1[m * 256 + k] = f2b(k < 128 ? Wr1[k * 128 + m] : Wo1[(k - 128) * 128 + m]);
    if (k == 0) bias3[m] = (m < 128) ? 0.f : br3[m - 128];
}

// ---------------- x -> bf16 into ax cols 128..255 ----------------

__global__ __launch_bounds__(256) void convert_x_kernel(const float* __restrict__ x,
                                                        u16* __restrict__ ax) {
    int idx = blockIdx.x * 256 + threadIdx.x;
    if (idx >= NN * 32) return;
    int row = idx >> 5, q = idx & 31;
    float4 v = *(const float4*)(x + (size_t)row * 128 + q * 4);
    u16 r[4] = {f2b(v.x), f2b(v.y), f2b(v.z), f2b(v.w)};
    *(u32*)(ax + (size_t)row * 256 + 128 + q * 4) = ((u32)r[1] << 16) | r[0];
    *(u32*)(ax + (size_t)row * 256 + 128 + q * 4 + 2) = ((u32)r[3] << 16) | r[2];
}

// ---------------- bf16 pull: agg over neighbors, bf16 out ----------------
// Xu: gather base (uint units, row stride 128 uints = 256 bf16); outu: same stride.

__global__ __launch_bounds__(256) void pull_bf_kernel(const u32* __restrict__ Xu,
                                                      const int* __restrict__ ofs,
                                                      const int* __restrict__ srcl,
                                                      u32* __restrict__ outu) {
    int node = (blockIdx.x * 256 + threadIdx.x) >> 6;
    int lane = threadIdx.x & 63;
    if (node >= NN) return;
    int lo = ofs[node], hi = ofs[node + 1];
    float ax = 0.f, ay = 0.f;
    int j = lo;
    for (; j + 3 < hi; j += 4) {
        int s0 = srcl[j], s1 = srcl[j + 1], s2 = srcl[j + 2], s3 = srcl[j + 3];
        u32 v0 = Xu[s0 * 128 + lane];
        u32 v1 = Xu[s1 * 128 + lane];
        u32 v2 = Xu[s2 * 128 + lane];
        u32 v3 = Xu[s3 * 128 + lane];
        ax += (b2f_lo(v0) + b2f_lo(v1)) + (b2f_lo(v2) + b2f_lo(v3));
        ay += (b2f_hi(v0) + b2f_hi(v1)) + (b2f_hi(v2) + b2f_hi(v3));
    }
    for (; j < hi; ++j) {
        u32 v = Xu[srcl[j] * 128 + lane];
        ax += b2f_lo(v);
        ay += b2f_hi(v);
    }
    outu[node * 128 + lane] = ((u32)f2b(ay) << 16) | f2b(ax);
}

// pull3: gather t3 (cols 0..127 of t3o3) + add o3 (cols 128..255), fp32 out.
__global__ __launch_bounds__(256) void pull3_kernel(const u32* __restrict__ Tu,
                                                    const int* __restrict__ ofs,
                                                    const int* __restrict__ srcl,
                                                    float* __restrict__ h3) {
    int node = (blockIdx.x * 256 + threadIdx.x) >> 6;
    int lane = threadIdx.x & 63;
    if (node >= NN) return;
    int lo = ofs[node], hi = ofs[node + 1];
    float ax = 0.f, ay = 0.f;
    int j = lo;
    for (; j + 3 < hi; j += 4) {
        int s0 = srcl[j], s1 = srcl[j + 1], s2 = srcl[j + 2], s3 = srcl[j + 3];
        u32 v0 = Tu[s0 * 128 + lane];
        u32 v1 = Tu[s1 * 128 + lane];
        u32 v2 = Tu[s2 * 128 + lane];
        u32 v3 = Tu[s3 * 128 + lane];
        ax += (b2f_lo(v0) + b2f_lo(v1)) + (b2f_lo(v2) + b2f_lo(v3));
        ay += (b2f_hi(v0) + b2f_hi(v1)) + (b2f_hi(v2) + b2f_hi(v3));
    }
    for (; j < hi; ++j) {
        u32 v = Tu[srcl[j] * 128 + lane];
        ax += b2f_lo(v);
        ay += b2f_hi(v);
    }
    u32 o = Tu[node * 128 + 64 + lane];
    float2 r;
    r.x = ax + b2f_lo(o);
    r.y = ay + b2f_hi(o);
    *(float2*)(h3 + (size_t)node * 128 + lane * 2) = r;
}

// ---------------- bf16 MFMA GEMM: C = relu?(A @ BT^T + bias), K=256 fixed ----------------
// A: [N x 256] bf16 (ld 256). BT: [M x 256] bf16. C: bf16 at ldc/coloff.
// Block: 256 thr = 4 waves (2x2), tile 128x128, wave tile 64x64, 16x16x32 MFMA.

__global__ __launch_bounds__(256, 2) void gemm_bf_kernel(
    const u16* __restrict__ A, const u16* __restrict__ BT,
    const float* __restrict__ bias, u16* __restrict__ C,
    int ldc, int coloff, int relu) {
    __shared__ alignas(16) u16 As[128 * 32];
    __shared__ alignas(16) u16 Bs[128 * 32];
    const int t = threadIdx.x;
    const int lane = t & 63, wid = t >> 6;
    const int quad = lane >> 4, l16 = lane & 15;
    const int wm = wid >> 1, wn = wid & 1;
    const int row0 = blockIdx.y * 128, c0 = blockIdx.x * 128;

    frag_cd acc[4][4];
#pragma unroll
    for (int i = 0; i < 4; ++i)
#pragma unroll
        for (int j = 0; j < 4; ++j) acc[i][j] = (frag_cd)0.f;

    // staging chunk geometry: chunk c (0..511) -> LDS offset c*16B, row=c>>2, koff=(c&3)*8 ush
    const int ca = t, cb = t + 256;
    const int ra = ca >> 2, oa = (ca & 3) * 8;
    const int rb = cb >> 2, ob = (cb & 3) * 8;
    const int garow = min(row0 + ra, NN - 1);
    const int gbrow = min(row0 + rb, NN - 1);
    const size_t gA1 = (size_t)garow * 256 + oa;
    const size_t gA2 = (size_t)gbrow * 256 + ob;
    const size_t gB1 = (size_t)(c0 + ra) * 256 + oa;
    const size_t gB2 = (size_t)(c0 + rb) * 256 + ob;

    for (int kk = 0; kk < 256; kk += 32) {
        __syncthreads();
        gl_lds16(A + gA1 + kk, &As[ca * 8]);
        gl_lds16(A + gA2 + kk, &As[cb * 8]);
        gl_lds16(BT + gB1 + kk, &Bs[ca * 8]);
        gl_lds16(BT + gB2 + kk, &Bs[cb * 8]);
        __syncthreads();

        frag_ab a[4], b[4];
#pragma unroll
        for (int mt = 0; mt < 4; ++mt)
            a[mt] = *(const frag_ab*)&As[(wm * 64 + mt * 16 + l16) * 32 + quad * 8];
#pragma unroll
        for (int nt = 0; nt < 4; ++nt)
            b[nt] = *(const frag_ab*)&Bs[(wn * 64 + nt * 16 + l16) * 32 + quad * 8];
#pragma unroll
        for (int mt = 0; mt < 4; ++mt)
#pragma unroll
            for (int nt = 0; nt < 4; ++nt)
                acc[mt][nt] = __builtin_amdgcn_mfma_f32_16x16x32_bf16(
                    a[mt], b[nt], acc[mt][nt], 0, 0, 0);
    }

#pragma unroll
    for (int nt = 0; nt < 4; ++nt) {
        int col = c0 + wn * 64 + nt * 16 + l16;
        float bv = bias[col];
#pragma unroll
        for (int mt = 0; mt < 4; ++mt) {
#pragma unroll
            for (int r = 0; r < 4; ++r) {
                int row = row0 + wm * 64 + mt * 16 + quad * 4 + r;
                if (row < NN) {
                    float v = acc[mt][nt][r] + bv;
                    if (relu) v = fmaxf(v, 0.f);
                    C[(size_t)row * ldc + coloff + col] = f2b(v);
                }
            }
        }
    }
}

// ---------------- mean pool + head ----------------

__device__ inline int lower_bound_i(const int* a, int n, int v) {
    int lo = 0, hi = n;
    while (lo < hi) {
        int m = (lo + hi) >> 1;
        if (a[m] < v) lo = m + 1; else hi = m;
    }
    return lo;
}

__global__ __launch_bounds__(128) void pool_kernel(const float* __restrict__ h,
                                                   const int* __restrict__ batch,
                                                   float* __restrict__ pooled) {
    int g = blockIdx.x, c = threadIdx.x;
    int lo = lower_bound_i(batch, NN, g);
    int hi = lower_bound_i(batch, NN, g + 1);
    float s = 0.f;
    for (int i = lo; i < hi; ++i) s += h[(size_t)i * 128 + c];
    pooled[g * 128 + c] = s / fmaxf((float)(hi - lo), 1.f);
}

__global__ __launch_bounds__(64) void head_kernel(const float* __restrict__ pooled,
                                                  const float* __restrict__ W1,
                                                  const float* __restrict__ b1,
                                                  const float* __restrict__ W2,
                                                  const float* __restrict__ b2,
                                                  float* __restrict__ out) {
    __shared__ float p[128];
    __shared__ float hid[40];
    int g = blockIdx.x, t = threadIdx.x;
    p[t] = pooled[g * 128 + t];
    p[t + 64] = pooled[g * 128 + 64 + t];
    __syncthreads();
    if (t < 40) {
        float s = b1[t];
        for (int k = 0; k < 128; ++k) s += p[k] * W1[k * 40 + t];
        hid[t] = s;
    }
    __syncthreads();
    if (t < 10) {
        float s = b2[t];
        for (int j = 0; j < 40; ++j) s += hid[j] * W2[j * 10 + t];
        out[g * 10 + t] = s;
    }
}

// ---------------- launch ----------------

extern "C" void kernel_launch(void* const* d_in, const int* in_sizes, int n_in,
                              void* d_out, int out_size, void* d_ws, size_t ws_size,
                              hipStream_t stream) {
    const float* x   = (const float*)d_in[0];
    const int* ei    = (const int*)d_in[1];
    const int* batch = (const int*)d_in[2];
    const float* Wr1 = (const float*)d_in[3];
    const float* br1 = (const float*)d_in[4];
    const float* Wo1 = (const float*)d_in[5];
    const float* Wr2 = (const float*)d_in[6];
    const float* br2 = (const float*)d_in[7];
    const float* Wo2 = (const float*)d_in[8];
    const float* Wr3 = (const float*)d_in[9];
    const float* br3 = (const float*)d_in[10];
    const float* Wo3 = (const float*)d_in[11];
    const float* W1  = (const float*)d_in[12];
    const float* b1  = (const float*)d_in[13];
    const float* W2  = (const float*)d_in[14];
    const float* b2  = (const float*)d_in[15];
    float* out = (float*)d_out;

    char* ws = (char*)d_ws;
    size_t off = 0;
    auto alloc = [&](size_t bytes) {
        void* p = ws + off;
        off += (bytes + 255) & ~(size_t)255;
        return p;
    };
    int* ofs   = (int*)alloc((NN + 1) * sizeof(int));
    int* cur   = (int*)alloc(NN * sizeof(int));
    int* bcur  = (int*)alloc(256 * sizeof(int));
    int* srcl  = (int*)alloc((size_t)EE * sizeof(int));
    u16* ax    = (u16*)alloc((size_t)NN * 256 * 2);   // cols 0-127 agg(x), 128-255 x_bf
    u16* ah1   = (u16*)alloc((size_t)NN * 256 * 2);   // cols 0-127 agg(h1), 128-255 h1
    u16* h2    = (u16*)alloc((size_t)NN * 256 * 2);
    u16* t3o3  = (u16*)alloc((size_t)NN * 256 * 2);   // cols 0-127 t3, 128-255 o3
    float* h3  = (float*)alloc((size_t)NN * 128 * sizeof(float));
    float* pooled = (float*)alloc((size_t)GG * 128 * sizeof(float));
    u16* BT1   = (u16*)alloc(128 * 256 * 2);
    u16* BT2   = (u16*)alloc(256 * 256 * 2);
    u16* BT3   = (u16*)alloc(256 * 256 * 2);
    float* bias3 = (float*)alloc(256 * sizeof(float));
    u32* pairs = (u32*)h3;   // overlay: pairs lifetime (CSR build) precedes h3

    // CSR by dst
    hipMemsetAsync(cur, 0, NN * sizeof(int), stream);
    hist_kernel<<<EE / 256, 256, 0, stream>>>(ei, cur);
    scan_kernel<<<1, 1024, 0, stream>>>(cur, ofs);
    bucket_init_kernel<<<1, 256, 0, stream>>>(ofs, bcur);
    bscatter_kernel<<<(EE + 4095) / 4096, 256, 0, stream>>>(ei, bcur, pairs);
    bfill_kernel<<<NB, 256, 0, stream>>>(ofs, pairs, srcl);

    // weights + x conversion
    prep_w_kernel<<<256, 256, 0, stream>>>(Wr1, Wo1, Wr2, Wo2, Wr3, Wo3, br3,
                                           BT1, BT2, BT3, bias3);
    convert_x_kernel<<<(NN * 32 + 255) / 256, 256, 0, stream>>>(x, ax);

    // conv1
    pull_bf_kernel<<<NN * 64 / 256, 256, 0, stream>>>((const u32*)ax + 64, ofs, srcl, (u32*)ax);
    gemm_bf_kernel<<<dim3(1, 391), 256, 0, stream>>>(ax, BT1, br1, ah1, 256, 128, 1);
    // conv2
    pull_bf_kernel<<<NN * 64 / 256, 256, 0, stream>>>((const u32*)ah1 + 64, ofs, srcl, (u32*)ah1);
    gemm_bf_kernel<<<dim3(2, 391), 256, 0, stream>>>(ah1, BT2, br2, h2, 256, 0, 1);
    // conv3: [t3|o3] = h2 @ [Wr3|Wo3] (+ [0|br3])
    gemm_bf_kernel<<<dim3(2, 391), 256, 0, stream>>>(h2, BT3, bias3, t3o3, 256, 0, 0);
    // h3 = agg(t3) + o3  (fp32)
    pull3_kernel<<<NN * 64 / 256, 256, 0, stream>>>((const u32*)t3o3, ofs, srcl, h3);

    // pool + head
    pool_kernel<<<GG, 128, 0, stream>>>(h3, batch, pooled);
    head_kernel<<<GG, 64, 0, stream>>>(pooled, W1, b1, W2, b2, out);
}

// Round 4
// 430.112 us; speedup vs baseline: 2.4646x; 1.3422x over previous
//
#include <hip/hip_runtime.h>
#include <hip/hip_bf16.h>
#include <cstddef>

#define NN 50000
#define EE 1600000
#define GG 512
#define NB 196        // ceil(NN/256) buckets of 256 nodes
#define BSTRIDE 16384 // fixed pairs-region capacity per bucket (max span ~8600)
#define BCAP 10240    // LDS staging per bucket

typedef unsigned int u32;
typedef unsigned short u16;
typedef __attribute__((ext_vector_type(8))) short frag_ab;   // 8 bf16 = 4 VGPRs
typedef __attribute__((ext_vector_type(4))) float frag_cd;   // 4 fp32 acc

__device__ __forceinline__ void gl_lds16(const void* g, void* l) {
    __builtin_amdgcn_global_load_lds(
        (const __attribute__((address_space(1))) u32*)g,
        (__attribute__((address_space(3))) u32*)l, 16, 0, 0);
}
__device__ __forceinline__ float b2f_lo(u32 v) { return __uint_as_float(v << 16); }
__device__ __forceinline__ float b2f_hi(u32 v) { return __uint_as_float(v & 0xffff0000u); }
__device__ __forceinline__ u16 f2b(float x) {
    __hip_bfloat16 h = __float2bfloat16(x);
    return *(u16*)&h;
}

// ---------------- CSR build (no global scan, no histogram kernel) ----------------

// Pass 1: bin edges by dst>>8 into fixed-capacity bucket regions.
__global__ __launch_bounds__(256) void bscatter_kernel(const int* __restrict__ ei,
                                                       int* __restrict__ bcnt,
                                                       u32* __restrict__ pairs) {
    __shared__ int lcnt[NB];
    __shared__ int lbase[NB];
    __shared__ unsigned short lpos[4096];
    int t = threadIdx.x;
    int e0 = blockIdx.x * 4096;
    for (int i = t; i < NB; i += 256) lcnt[i] = 0;
    __syncthreads();
#pragma unroll
    for (int i = 0; i < 16; ++i) {
        int e = e0 + i * 256 + t;
        if (e < EE) {
            int b = ei[EE + e] >> 8;
            lpos[i * 256 + t] = (unsigned short)atomicAdd(&lcnt[b], 1);
        }
    }
    __syncthreads();
    for (int i = t; i < NB; i += 256) lbase[i] = atomicAdd(&bcnt[i], lcnt[i]);
    __syncthreads();
#pragma unroll
    for (int i = 0; i < 16; ++i) {
        int e = e0 + i * 256 + t;
        if (e < EE) {
            int src = ei[e], dst = ei[EE + e];
            int b = dst >> 8;
            int pos = lbase[b] + (int)lpos[i * 256 + t];
            pairs[(size_t)b * BSTRIDE + pos] = ((u32)src << 8) | (u32)(dst & 255);
        }
    }
}

// Tiny scan over 196 bucket counts -> bucket CSR bases (one block).
__global__ __launch_bounds__(256) void bscan_kernel(const int* __restrict__ bcnt,
                                                    int* __restrict__ bbase) {
    __shared__ int sc[256];
    int t = threadIdx.x;
    int c = (t < NB) ? bcnt[t] : 0;
    sc[t] = c;
    __syncthreads();
    for (int off = 1; off < 256; off <<= 1) {
        int v = (t >= off) ? sc[t - off] : 0;
        __syncthreads();
        sc[t] += v;
        __syncthreads();
    }
    if (t < NB) bbase[t] = sc[t] - c;
}

// Pass 2: per bucket: node histogram + LDS scan -> ofs; LDS scatter -> sequential srcl.
__global__ __launch_bounds__(256) void bfill_kernel(const u32* __restrict__ pairs,
                                                    const int* __restrict__ bcnt,
                                                    const int* __restrict__ bbase,
                                                    int* __restrict__ ofs,
                                                    int* __restrict__ srcl) {
    __shared__ int lcnt[256];
    __shared__ int sc[256];
    __shared__ int lcur[256];
    __shared__ int lbuf[BCAP];
    int b = blockIdx.x, t = threadIdx.x;
    const u32* pp = pairs + (size_t)b * BSTRIDE;
    int span = bcnt[b], base = bbase[b];
    lcnt[t] = 0;
    __syncthreads();
    for (int j = t; j < span; j += 256) atomicAdd(&lcnt[pp[j] & 255u], 1);
    __syncthreads();
    int c = lcnt[t];
    sc[t] = c;
    __syncthreads();
    for (int off = 1; off < 256; off <<= 1) {
        int v = (t >= off) ? sc[t - off] : 0;
        __syncthreads();
        sc[t] += v;
        __syncthreads();
    }
    int excl = sc[t] - c;
    int node = b * 256 + t;
    if (node < NN) ofs[node] = base + excl;
    if (b == NB - 1 && t == 0) ofs[NN] = EE;
    lcur[t] = excl;
    __syncthreads();
    for (int j = t; j < span; j += 256) {
        u32 p = pp[j];
        int pos = atomicAdd(&lcur[p & 255u], 1);
        int src = (int)(p >> 8);
        if (pos < BCAP) lbuf[pos] = src;
        else srcl[base + pos] = src;
    }
    __syncthreads();
    int lim = span < BCAP ? span : BCAP;
    for (int j = t; j < lim; j += 256) srcl[base + j] = lbuf[j];
}

// ---------------- weight prep: BT[M][256] bf16 (pre-transposed concat) ----------------

__global__ __launch_bounds__(256) void prep_w_kernel(
    const float* __restrict__ Wr1, const float* __restrict__ Wo1,
    const float* __restrict__ Wr2, const float* __restrict__ Wo2,
    const float* __restrict__ Wr3, const float* __restrict__ Wo3,
    const float* __restrict__ br3,
    u16* __restrict__ BT1, u16* __restrict__ BT2, u16* __restrict__ BT3,
    float* __restrict__ bias3) {
    int m = blockIdx.x;          // output col
    int k = threadIdx.x;         // reduction idx
    BT2[m * 256 + k] = f2b(k < 128 ? Wr2[k * 256 + m] : Wo2[(k - 128) * 256 + m]);
    BT3[m * 256 + k] = f2b(m < 128 ? Wr3[k * 128 + m] : Wo3[k * 128 + (m - 128)]);
    if (m < 128)
        BT1[m * 256 + k] = f2b(k < 128 ? Wr1[k * 128 + m] : Wo1[(k - 128) * 128 + m]);
    if (k == 0) bias3[m] = (m < 128) ? 0.f : br3[m - 128];
}

// ---------------- x -> bf16 into ax cols 128..255 ----------------

__global__ __launch_bounds__(256) void convert_x_kernel(const float* __restrict__ x,
                                                        u16* __restrict__ ax) {
    int idx = blockIdx.x * 256 + threadIdx.x;
    if (idx >= NN * 32) return;
    int row = idx >> 5, q = idx & 31;
    float4 v = *(const float4*)(x + (size_t)row * 128 + q * 4);
    u16 r[4] = {f2b(v.x), f2b(v.y), f2b(v.z), f2b(v.w)};
    *(u32*)(ax + (size_t)row * 256 + 128 + q * 4) = ((u32)r[1] << 16) | r[0];
    *(u32*)(ax + (size_t)row * 256 + 128 + q * 4 + 2) = ((u32)r[3] << 16) | r[2];
}

// ---------------- bf16 pull: agg over neighbors (one wave per node) ----------------

__global__ __launch_bounds__(256) void pull_bf_kernel(const u32* __restrict__ Xu,
                                                      const int* __restrict__ ofs,
                                                      const int* __restrict__ srcl,
                                                      u32* __restrict__ outu) {
    int node = (blockIdx.x * 256 + threadIdx.x) >> 6;
    int lane = threadIdx.x & 63;
    if (node >= NN) return;
    int lo = ofs[node], hi = ofs[node + 1];
    float ax = 0.f, ay = 0.f;
    int j = lo;
    for (; j + 3 < hi; j += 4) {
        int s0 = srcl[j], s1 = srcl[j + 1], s2 = srcl[j + 2], s3 = srcl[j + 3];
        u32 v0 = Xu[s0 * 128 + lane];
        u32 v1 = Xu[s1 * 128 + lane];
        u32 v2 = Xu[s2 * 128 + lane];
        u32 v3 = Xu[s3 * 128 + lane];
        ax += (b2f_lo(v0) + b2f_lo(v1)) + (b2f_lo(v2) + b2f_lo(v3));
        ay += (b2f_hi(v0) + b2f_hi(v1)) + (b2f_hi(v2) + b2f_hi(v3));
    }
    for (; j < hi; ++j) {
        u32 v = Xu[srcl[j] * 128 + lane];
        ax += b2f_lo(v);
        ay += b2f_hi(v);
    }
    outu[node * 128 + lane] = ((u32)f2b(ay) << 16) | f2b(ax);
}

// pull3: gather t3 (cols 0..127) + add o3 (cols 128..255), fp32 out.
__global__ __launch_bounds__(256) void pull3_kernel(const u32* __restrict__ Tu,
                                                    const int* __restrict__ ofs,
                                                    const int* __restrict__ srcl,
                                                    float* __restrict__ h3) {
    int node = (blockIdx.x * 256 + threadIdx.x) >> 6;
    int lane = threadIdx.x & 63;
    if (node >= NN) return;
    int lo = ofs[node], hi = ofs[node + 1];
    float ax = 0.f, ay = 0.f;
    int j = lo;
    for (; j + 3 < hi; j += 4) {
        int s0 = srcl[j], s1 = srcl[j + 1], s2 = srcl[j + 2], s3 = srcl[j + 3];
        u32 v0 = Tu[s0 * 128 + lane];
        u32 v1 = Tu[s1 * 128 + lane];
        u32 v2 = Tu[s2 * 128 + lane];
        u32 v3 = Tu[s3 * 128 + lane];
        ax += (b2f_lo(v0) + b2f_lo(v1)) + (b2f_lo(v2) + b2f_lo(v3));
        ay += (b2f_hi(v0) + b2f_hi(v1)) + (b2f_hi(v2) + b2f_hi(v3));
    }
    for (; j < hi; ++j) {
        u32 v = Tu[srcl[j] * 128 + lane];
        ax += b2f_lo(v);
        ay += b2f_hi(v);
    }
    u32 o = Tu[node * 128 + 64 + lane];
    float2 r;
    r.x = ax + b2f_lo(o);
    r.y = ay + b2f_hi(o);
    *(float2*)(h3 + (size_t)node * 128 + lane * 2) = r;
}

// ---------------- bf16 MFMA GEMM: C = relu?(A @ BT^T + bias), K=256 ----------------

__global__ __launch_bounds__(256, 2) void gemm_bf_kernel(
    const u16* __restrict__ A, const u16* __restrict__ BT,
    const float* __restrict__ bias, u16* __restrict__ C,
    int ldc, int coloff, int relu) {
    __shared__ alignas(16) u16 As[128 * 32];
    __shared__ alignas(16) u16 Bs[128 * 32];
    const int t = threadIdx.x;
    const int lane = t & 63, wid = t >> 6;
    const int quad = lane >> 4, l16 = lane & 15;
    const int wm = wid >> 1, wn = wid & 1;
    const int row0 = blockIdx.y * 128, c0 = blockIdx.x * 128;

    frag_cd acc[4][4];
#pragma unroll
    for (int i = 0; i < 4; ++i)
#pragma unroll
        for (int j = 0; j < 4; ++j) acc[i][j] = (frag_cd)0.f;

    const int ca = t, cb = t + 256;
    const int ra = ca >> 2, oa = (ca & 3) * 8;
    const int rb = cb >> 2, ob = (cb & 3) * 8;
    const int garow = min(row0 + ra, NN - 1);
    const int gbrow = min(row0 + rb, NN - 1);
    const size_t gA1 = (size_t)garow * 256 + oa;
    const size_t gA2 = (size_t)gbrow * 256 + ob;
    const size_t gB1 = (size_t)(c0 + ra) * 256 + oa;
    const size_t gB2 = (size_t)(c0 + rb) * 256 + ob;

    for (int kk = 0; kk < 256; kk += 32) {
        __syncthreads();
        gl_lds16(A + gA1 + kk, &As[ca * 8]);
        gl_lds16(A + gA2 + kk, &As[cb * 8]);
        gl_lds16(BT + gB1 + kk, &Bs[ca * 8]);
        gl_lds16(BT + gB2 + kk, &Bs[cb * 8]);
        __syncthreads();

        frag_ab a[4], b[4];
#pragma unroll
        for (int mt = 0; mt < 4; ++mt)
            a[mt] = *(const frag_ab*)&As[(wm * 64 + mt * 16 + l16) * 32 + quad * 8];
#pragma unroll
        for (int nt = 0; nt < 4; ++nt)
            b[nt] = *(const frag_ab*)&Bs[(wn * 64 + nt * 16 + l16) * 32 + quad * 8];
#pragma unroll
        for (int mt = 0; mt < 4; ++mt)
#pragma unroll
            for (int nt = 0; nt < 4; ++nt)
                acc[mt][nt] = __builtin_amdgcn_mfma_f32_16x16x32_bf16(
                    a[mt], b[nt], acc[mt][nt], 0, 0, 0);
    }

#pragma unroll
    for (int nt = 0; nt < 4; ++nt) {
        int col = c0 + wn * 64 + nt * 16 + l16;
        float bv = bias[col];
#pragma unroll
        for (int mt = 0; mt < 4; ++mt) {
#pragma unroll
            for (int r = 0; r < 4; ++r) {
                int row = row0 + wm * 64 + mt * 16 + quad * 4 + r;
                if (row < NN) {
                    float v = acc[mt][nt][r] + bv;
                    if (relu) v = fmaxf(v, 0.f);
                    C[(size_t)row * ldc + coloff + col] = f2b(v);
                }
            }
        }
    }
}

// ---------------- fused mean-pool + head ----------------

__device__ inline int lower_bound_i(const int* a, int n, int v) {
    int lo = 0, hi = n;
    while (lo < hi) {
        int m = (lo + hi) >> 1;
        if (a[m] < v) lo = m + 1; else hi = m;
    }
    return lo;
}

__global__ __launch_bounds__(128) void pool_head_kernel(const float* __restrict__ h,
                                                        const int* __restrict__ batch,
                                                        const float* __restrict__ W1,
                                                        const float* __restrict__ b1,
                                                        const float* __restrict__ W2,
                                                        const float* __restrict__ b2,
                                                        float* __restrict__ out) {
    __shared__ float p[128];
    __shared__ float hid[40];
    int g = blockIdx.x, t = threadIdx.x;
    int lo = lower_bound_i(batch, NN, g);
    int hi = lower_bound_i(batch, NN, g + 1);
    float s = 0.f;
    for (int i = lo; i < hi; ++i) s += h[(size_t)i * 128 + t];
    p[t] = s / fmaxf((float)(hi - lo), 1.f);
    __syncthreads();
    if (t < 40) {
        float v = b1[t];
        for (int k = 0; k < 128; ++k) v += p[k] * W1[k * 40 + t];
        hid[t] = v;
    }
    __syncthreads();
    if (t < 10) {
        float v = b2[t];
        for (int j = 0; j < 40; ++j) v += hid[j] * W2[j * 10 + t];
        out[g * 10 + t] = v;
    }
}

// ---------------- launch ----------------

extern "C" void kernel_launch(void* const* d_in, const int* in_sizes, int n_in,
                              void* d_out, int out_size, void* d_ws, size_t ws_size,
                              hipStream_t stream) {
    const float* x   = (const float*)d_in[0];
    const int* ei    = (const int*)d_in[1];
    const int* batch = (const int*)d_in[2];
    const float* Wr1 = (const float*)d_in[3];
    const float* br1 = (const float*)d_in[4];
    const float* Wo1 = (const float*)d_in[5];
    const float* Wr2 = (const float*)d_in[6];
    const float* br2 = (const float*)d_in[7];
    const float* Wo2 = (const float*)d_in[8];
    const float* Wr3 = (const float*)d_in[9];
    const float* br3 = (const float*)d_in[10];
    const float* Wo3 = (const float*)d_in[11];
    const float* W1  = (const float*)d_in[12];
    const float* b1  = (const float*)d_in[13];
    const float* W2  = (const float*)d_in[14];
    const float* b2  = (const float*)d_in[15];
    float* out = (float*)d_out;

    char* ws = (char*)d_ws;
    size_t off = 0;
    auto alloc = [&](size_t bytes) {
        void* p = ws + off;
        off += (bytes + 255) & ~(size_t)255;
        return p;
    };
    int* ofs   = (int*)alloc((NN + 1) * sizeof(int));
    int* bcnt  = (int*)alloc(256 * sizeof(int));
    int* bbase = (int*)alloc(256 * sizeof(int));
    int* srcl  = (int*)alloc((size_t)EE * sizeof(int));
    u16* ax    = (u16*)alloc((size_t)NN * 256 * 2);   // cols 0-127 agg, 128-255 x_bf
    u16* ah1   = (u16*)alloc((size_t)NN * 256 * 2);
    u16* h2    = (u16*)alloc((size_t)NN * 256 * 2);
    u16* t3o3  = (u16*)alloc((size_t)NN * 256 * 2);   // cols 0-127 t3, 128-255 o3
    float* h3  = (float*)alloc((size_t)NN * 128 * sizeof(float));
    u16* BT1   = (u16*)alloc(128 * 256 * 2);
    u16* BT2   = (u16*)alloc(256 * 256 * 2);
    u16* BT3   = (u16*)alloc(256 * 256 * 2);
    float* bias3 = (float*)alloc(256 * sizeof(float));
    u32* pairs = (u32*)h3;   // overlay: pairs (12.85 MB, CSR build) precedes h3 writes

    // CSR by dst: fixed bucket regions -> tiny bucket scan -> in-bucket hist/scan/scatter
    hipMemsetAsync(bcnt, 0, 256 * sizeof(int), stream);
    bscatter_kernel<<<(EE + 4095) / 4096, 256, 0, stream>>>(ei, bcnt, pairs);
    bscan_kernel<<<1, 256, 0, stream>>>(bcnt, bbase);
    bfill_kernel<<<NB, 256, 0, stream>>>(pairs, bcnt, bbase, ofs, srcl);

    // weights + x conversion
    prep_w_kernel<<<256, 256, 0, stream>>>(Wr1, Wo1, Wr2, Wo2, Wr3, Wo3, br3,
                                           BT1, BT2, BT3, bias3);
    convert_x_kernel<<<(NN * 32 + 255) / 256, 256, 0, stream>>>(x, ax);

    // conv1
    pull_bf_kernel<<<NN * 64 / 256, 256, 0, stream>>>((const u32*)ax + 64, ofs, srcl, (u32*)ax);
    gemm_bf_kernel<<<dim3(1, 391), 256, 0, stream>>>(ax, BT1, br1, ah1, 256, 128, 1);
    // conv2
    pull_bf_kernel<<<NN * 64 / 256, 256, 0, stream>>>((const u32*)ah1 + 64, ofs, srcl, (u32*)ah1);
    gemm_bf_kernel<<<dim3(2, 391), 256, 0, stream>>>(ah1, BT2, br2, h2, 256, 0, 1);
    // conv3: [t3|o3] = h2 @ [Wr3|Wo3] (+ [0|br3])
    gemm_bf_kernel<<<dim3(2, 391), 256, 0, stream>>>(h2, BT3, bias3, t3o3, 256, 0, 0);
    // h3 = agg(t3) + o3  (fp32)
    pull3_kernel<<<NN * 64 / 256, 256, 0, stream>>>((const u32*)t3o3, ofs, srcl, h3);

    // fused mean pool + head
    pool_head_kernel<<<GG, 128, 0, stream>>>(h3, batch, W1, b1, W2, b2, out);
}

// Round 5
// 396.147 us; speedup vs baseline: 2.6759x; 1.0857x over previous
//
#include <hip/hip_runtime.h>
#include <hip/hip_bf16.h>
#include <cstddef>

#define NN 50000
#define EE 1600000
#define GG 512
#define NB 196        // ceil(NN/256) buckets of 256 nodes
#define BSTRIDE 16384 // fixed pairs-region capacity per bucket (max span ~8600)
#define BCAP 10240    // LDS staging per bucket

typedef unsigned int u32;
typedef unsigned short u16;
typedef __attribute__((ext_vector_type(8))) short frag_ab;   // 8 bf16 = 4 VGPRs
typedef __attribute__((ext_vector_type(4))) float frag_cd;   // 4 fp32 acc

__device__ __forceinline__ void gl_lds16(const void* g, void* l) {
    __builtin_amdgcn_global_load_lds(
        (const __attribute__((address_space(1))) u32*)g,
        (__attribute__((address_space(3))) u32*)l, 16, 0, 0);
}
__device__ __forceinline__ float b2f_lo(u32 v) { return __uint_as_float(v << 16); }
__device__ __forceinline__ float b2f_hi(u32 v) { return __uint_as_float(v & 0xffff0000u); }
__device__ __forceinline__ u16 f2b(float x) {
    __hip_bfloat16 h = __float2bfloat16(x);
    return *(u16*)&h;
}
__device__ __forceinline__ u32 pack2(float lo, float hi) {
    return ((u32)f2b(hi) << 16) | f2b(lo);
}

// ---------------- CSR build ----------------

// Pass 1: bin edges by dst>>8 into fixed-capacity bucket regions.
__global__ __launch_bounds__(256) void bscatter_kernel(const int* __restrict__ ei,
                                                       int* __restrict__ bcnt,
                                                       u32* __restrict__ pairs) {
    __shared__ int lcnt[NB];
    __shared__ int lbase[NB];
    __shared__ unsigned short lpos[4096];
    int t = threadIdx.x;
    int e0 = blockIdx.x * 4096;
    for (int i = t; i < NB; i += 256) lcnt[i] = 0;
    __syncthreads();
#pragma unroll
    for (int i = 0; i < 16; ++i) {
        int e = e0 + i * 256 + t;
        if (e < EE) {
            int b = ei[EE + e] >> 8;
            lpos[i * 256 + t] = (unsigned short)atomicAdd(&lcnt[b], 1);
        }
    }
    __syncthreads();
    for (int i = t; i < NB; i += 256) lbase[i] = atomicAdd(&bcnt[i], lcnt[i]);
    __syncthreads();
#pragma unroll
    for (int i = 0; i < 16; ++i) {
        int e = e0 + i * 256 + t;
        if (e < EE) {
            int src = ei[e], dst = ei[EE + e];
            int b = dst >> 8;
            int pos = lbase[b] + (int)lpos[i * 256 + t];
            pairs[(size_t)b * BSTRIDE + pos] = ((u32)src << 8) | (u32)(dst & 255);
        }
    }
}

// Pass 2: per bucket: inline 196-count scan -> bucket base; node histogram + LDS
// scan -> ofs; LDS scatter -> sequential srcl.
__global__ __launch_bounds__(256) void bfill_kernel(const u32* __restrict__ pairs,
                                                    const int* __restrict__ bcnt,
                                                    int* __restrict__ ofs,
                                                    int* __restrict__ srcl) {
    __shared__ int sc[256];
    __shared__ int cnts[256];
    __shared__ int lcnt[256];
    __shared__ int lcur[256];
    __shared__ int lbuf[BCAP];
    int b = blockIdx.x, t = threadIdx.x;
    // inline scan of bucket counts (replaces separate bscan kernel)
    int c = (t < NB) ? bcnt[t] : 0;
    cnts[t] = c;
    sc[t] = c;
    lcnt[t] = 0;
    __syncthreads();
    for (int off = 1; off < 256; off <<= 1) {
        int v = (t >= off) ? sc[t - off] : 0;
        __syncthreads();
        sc[t] += v;
        __syncthreads();
    }
    int base = sc[b] - cnts[b];
    int span = cnts[b];
    const u32* pp = pairs + (size_t)b * BSTRIDE;
    for (int j = t; j < span; j += 256) atomicAdd(&lcnt[pp[j] & 255u], 1);
    __syncthreads();
    int nc = lcnt[t];
    sc[t] = nc;
    __syncthreads();
    for (int off = 1; off < 256; off <<= 1) {
        int v = (t >= off) ? sc[t - off] : 0;
        __syncthreads();
        sc[t] += v;
        __syncthreads();
    }
    int excl = sc[t] - nc;
    int node = b * 256 + t;
    if (node < NN) ofs[node] = base + excl;
    if (b == NB - 1 && t == 0) ofs[NN] = EE;
    lcur[t] = excl;
    __syncthreads();
    for (int j = t; j < span; j += 256) {
        u32 p = pp[j];
        int pos = atomicAdd(&lcur[p & 255u], 1);
        int src = (int)(p >> 8);
        if (pos < BCAP) lbuf[pos] = src;
        else srcl[base + pos] = src;
    }
    __syncthreads();
    int lim = span < BCAP ? span : BCAP;
    for (int j = t; j < lim; j += 256) srcl[base + j] = lbuf[j];
}

// ---------------- merged prep: x->bf16 (cols 128..255 of ax) + weight transpose ----------------

__global__ __launch_bounds__(256) void prep_kernel(
    const float* __restrict__ x, u16* __restrict__ ax,
    const float* __restrict__ Wr1, const float* __restrict__ Wo1,
    const float* __restrict__ Wr2, const float* __restrict__ Wo2,
    const float* __restrict__ Wr3, const float* __restrict__ Wo3,
    const float* __restrict__ br3,
    u16* __restrict__ BT1, u16* __restrict__ BT2, u16* __restrict__ BT3,
    float* __restrict__ bias3) {
    int bid = blockIdx.x, t = threadIdx.x;
    if (bid < NN * 32 / 256) {
        int idx = bid * 256 + t;
        int row = idx >> 5, q = idx & 31;
        float4 v = *(const float4*)(x + (size_t)row * 128 + q * 4);
        *(u32*)(ax + (size_t)row * 256 + 128 + q * 4) = pack2(v.x, v.y);
        *(u32*)(ax + (size_t)row * 256 + 128 + q * 4 + 2) = pack2(v.z, v.w);
    } else {
        int m = bid - NN * 32 / 256;   // 0..255 output col
        int k = t;                      // reduction idx
        BT2[m * 256 + k] = f2b(k < 128 ? Wr2[k * 256 + m] : Wo2[(k - 128) * 256 + m]);
        BT3[m * 256 + k] = f2b(m < 128 ? Wr3[k * 128 + m] : Wo3[k * 128 + (m - 128)]);
        if (m < 128)
            BT1[m * 256 + k] = f2b(k < 128 ? Wr1[k * 128 + m] : Wo1[(k - 128) * 128 + m]);
        if (k == 0) bias3[m] = (m < 128) ? 0.f : br3[m - 128];
    }
}

// ---------------- bf16 pull, wide-load form ----------------
// One wave per node. Lanes split: q=lane>>4 edge slot (4 edges/iter), l=lane&15
// channel group (8 ch each, dwordx4). Cross-quarter shfl reduction at end.

__global__ __launch_bounds__(256) void pull_bf_kernel(const u32* __restrict__ Xu,
                                                      const int* __restrict__ ofs,
                                                      const int* __restrict__ srcl,
                                                      u32* __restrict__ outu) {
    int node = (blockIdx.x * 256 + threadIdx.x) >> 6;
    int lane = threadIdx.x & 63;
    int q = lane >> 4, l = lane & 15;
    int lo = ofs[node], hi = ofs[node + 1];
    float acc[8];
#pragma unroll
    for (int i = 0; i < 8; ++i) acc[i] = 0.f;
    int j = lo;
    for (; j + 7 < hi; j += 8) {
        int sA = srcl[j + q], sB = srcl[j + 4 + q];
        uint4 vA = *(const uint4*)(Xu + (size_t)sA * 128 + l * 4);
        uint4 vB = *(const uint4*)(Xu + (size_t)sB * 128 + l * 4);
        acc[0] += b2f_lo(vA.x) + b2f_lo(vB.x);
        acc[1] += b2f_hi(vA.x) + b2f_hi(vB.x);
        acc[2] += b2f_lo(vA.y) + b2f_lo(vB.y);
        acc[3] += b2f_hi(vA.y) + b2f_hi(vB.y);
        acc[4] += b2f_lo(vA.z) + b2f_lo(vB.z);
        acc[5] += b2f_hi(vA.z) + b2f_hi(vB.z);
        acc[6] += b2f_lo(vA.w) + b2f_lo(vB.w);
        acc[7] += b2f_hi(vA.w) + b2f_hi(vB.w);
    }
    for (; j + 3 < hi; j += 4) {
        int s = srcl[j + q];
        uint4 v = *(const uint4*)(Xu + (size_t)s * 128 + l * 4);
        acc[0] += b2f_lo(v.x); acc[1] += b2f_hi(v.x);
        acc[2] += b2f_lo(v.y); acc[3] += b2f_hi(v.y);
        acc[4] += b2f_lo(v.z); acc[5] += b2f_hi(v.z);
        acc[6] += b2f_lo(v.w); acc[7] += b2f_hi(v.w);
    }
    if (j + q < hi) {
        int s = srcl[j + q];
        uint4 v = *(const uint4*)(Xu + (size_t)s * 128 + l * 4);
        acc[0] += b2f_lo(v.x); acc[1] += b2f_hi(v.x);
        acc[2] += b2f_lo(v.y); acc[3] += b2f_hi(v.y);
        acc[4] += b2f_lo(v.z); acc[5] += b2f_hi(v.z);
        acc[6] += b2f_lo(v.w); acc[7] += b2f_hi(v.w);
    }
#pragma unroll
    for (int i = 0; i < 8; ++i) {
        acc[i] += __shfl_xor(acc[i], 16, 64);
        acc[i] += __shfl_xor(acc[i], 32, 64);
    }
    if (q == 0) {
        uint4 r;
        r.x = pack2(acc[0], acc[1]);
        r.y = pack2(acc[2], acc[3]);
        r.z = pack2(acc[4], acc[5]);
        r.w = pack2(acc[6], acc[7]);
        *(uint4*)(outu + (size_t)node * 128 + l * 4) = r;
    }
}

// pull3: gather t3 (cols 0..127) + add o3 (cols 128..255), bf16 out (stride 64 u32).
__global__ __launch_bounds__(256) void pull3_kernel(const u32* __restrict__ Tu,
                                                    const int* __restrict__ ofs,
                                                    const int* __restrict__ srcl,
                                                    u32* __restrict__ h3u) {
    int node = (blockIdx.x * 256 + threadIdx.x) >> 6;
    int lane = threadIdx.x & 63;
    int q = lane >> 4, l = lane & 15;
    int lo = ofs[node], hi = ofs[node + 1];
    float acc[8];
#pragma unroll
    for (int i = 0; i < 8; ++i) acc[i] = 0.f;
    int j = lo;
    for (; j + 7 < hi; j += 8) {
        int sA = srcl[j + q], sB = srcl[j + 4 + q];
        uint4 vA = *(const uint4*)(Tu + (size_t)sA * 128 + l * 4);
        uint4 vB = *(const uint4*)(Tu + (size_t)sB * 128 + l * 4);
        acc[0] += b2f_lo(vA.x) + b2f_lo(vB.x);
        acc[1] += b2f_hi(vA.x) + b2f_hi(vB.x);
        acc[2] += b2f_lo(vA.y) + b2f_lo(vB.y);
        acc[3] += b2f_hi(vA.y) + b2f_hi(vB.y);
        acc[4] += b2f_lo(vA.z) + b2f_lo(vB.z);
        acc[5] += b2f_hi(vA.z) + b2f_hi(vB.z);
        acc[6] += b2f_lo(vA.w) + b2f_lo(vB.w);
        acc[7] += b2f_hi(vA.w) + b2f_hi(vB.w);
    }
    for (; j + 3 < hi; j += 4) {
        int s = srcl[j + q];
        uint4 v = *(const uint4*)(Tu + (size_t)s * 128 + l * 4);
        acc[0] += b2f_lo(v.x); acc[1] += b2f_hi(v.x);
        acc[2] += b2f_lo(v.y); acc[3] += b2f_hi(v.y);
        acc[4] += b2f_lo(v.z); acc[5] += b2f_hi(v.z);
        acc[6] += b2f_lo(v.w); acc[7] += b2f_hi(v.w);
    }
    if (j + q < hi) {
        int s = srcl[j + q];
        uint4 v = *(const uint4*)(Tu + (size_t)s * 128 + l * 4);
        acc[0] += b2f_lo(v.x); acc[1] += b2f_hi(v.x);
        acc[2] += b2f_lo(v.y); acc[3] += b2f_hi(v.y);
        acc[4] += b2f_lo(v.z); acc[5] += b2f_hi(v.z);
        acc[6] += b2f_lo(v.w); acc[7] += b2f_hi(v.w);
    }
#pragma unroll
    for (int i = 0; i < 8; ++i) {
        acc[i] += __shfl_xor(acc[i], 16, 64);
        acc[i] += __shfl_xor(acc[i], 32, 64);
    }
    if (q == 0) {
        uint4 o = *(const uint4*)(Tu + (size_t)node * 128 + 64 + l * 4);
        acc[0] += b2f_lo(o.x); acc[1] += b2f_hi(o.x);
        acc[2] += b2f_lo(o.y); acc[3] += b2f_hi(o.y);
        acc[4] += b2f_lo(o.z); acc[5] += b2f_hi(o.z);
        acc[6] += b2f_lo(o.w); acc[7] += b2f_hi(o.w);
        uint4 r;
        r.x = pack2(acc[0], acc[1]);
        r.y = pack2(acc[2], acc[3]);
        r.z = pack2(acc[4], acc[5]);
        r.w = pack2(acc[6], acc[7]);
        *(uint4*)(h3u + (size_t)node * 64 + l * 4) = r;
    }
}

// ---------------- bf16 MFMA GEMM: C = relu?(A @ BT^T + bias), K=256 ----------------

__global__ __launch_bounds__(256, 2) void gemm_bf_kernel(
    const u16* __restrict__ A, const u16* __restrict__ BT,
    const float* __restrict__ bias, u16* __restrict__ C,
    int ldc, int coloff, int relu) {
    __shared__ alignas(16) u16 As[128 * 32];
    __shared__ alignas(16) u16 Bs[128 * 32];
    const int t = threadIdx.x;
    const int lane = t & 63, wid = t >> 6;
    const int quad = lane >> 4, l16 = lane & 15;
    const int wm = wid >> 1, wn = wid & 1;
    const int row0 = blockIdx.y * 128, c0 = blockIdx.x * 128;

    frag_cd acc[4][4];
#pragma unroll
    for (int i = 0; i < 4; ++i)
#pragma unroll
        for (int j = 0; j < 4; ++j) acc[i][j] = (frag_cd)0.f;

    const int ca = t, cb = t + 256;
    const int ra = ca >> 2, oa = (ca & 3) * 8;
    const int rb = cb >> 2, ob = (cb & 3) * 8;
    const int garow = min(row0 + ra, NN - 1);
    const int gbrow = min(row0 + rb, NN - 1);
    const size_t gA1 = (size_t)garow * 256 + oa;
    const size_t gA2 = (size_t)gbrow * 256 + ob;
    const size_t gB1 = (size_t)(c0 + ra) * 256 + oa;
    const size_t gB2 = (size_t)(c0 + rb) * 256 + ob;

    for (int kk = 0; kk < 256; kk += 32) {
        __syncthreads();
        gl_lds16(A + gA1 + kk, &As[ca * 8]);
        gl_lds16(A + gA2 + kk, &As[cb * 8]);
        gl_lds16(BT + gB1 + kk, &Bs[ca * 8]);
        gl_lds16(BT + gB2 + kk, &Bs[cb * 8]);
        __syncthreads();

        frag_ab a[4], b[4];
#pragma unroll
        for (int mt = 0; mt < 4; ++mt)
            a[mt] = *(const frag_ab*)&As[(wm * 64 + mt * 16 + l16) * 32 + quad * 8];
#pragma unroll
        for (int nt = 0; nt < 4; ++nt)
            b[nt] = *(const frag_ab*)&Bs[(wn * 64 + nt * 16 + l16) * 32 + quad * 8];
#pragma unroll
        for (int mt = 0; mt < 4; ++mt)
#pragma unroll
            for (int nt = 0; nt < 4; ++nt)
                acc[mt][nt] = __builtin_amdgcn_mfma_f32_16x16x32_bf16(
                    a[mt], b[nt], acc[mt][nt], 0, 0, 0);
    }

#pragma unroll
    for (int nt = 0; nt < 4; ++nt) {
        int col = c0 + wn * 64 + nt * 16 + l16;
        float bv = bias[col];
#pragma unroll
        for (int mt = 0; mt < 4; ++mt) {
#pragma unroll
            for (int r = 0; r < 4; ++r) {
                int row = row0 + wm * 64 + mt * 16 + quad * 4 + r;
                if (row < NN) {
                    float v = acc[mt][nt][r] + bv;
                    if (relu) v = fmaxf(v, 0.f);
                    C[(size_t)row * ldc + coloff + col] = f2b(v);
                }
            }
        }
    }
}

// ---------------- fused mean-pool + head (h3 in bf16) ----------------

__device__ inline int lower_bound_i(const int* a, int n, int v) {
    int lo = 0, hi = n;
    while (lo < hi) {
        int m = (lo + hi) >> 1;
        if (a[m] < v) lo = m + 1; else hi = m;
    }
    return lo;
}

__global__ __launch_bounds__(128) void pool_head_kernel(const u32* __restrict__ h3u,
                                                        const int* __restrict__ batch,
                                                        const float* __restrict__ W1,
                                                        const float* __restrict__ b1,
                                                        const float* __restrict__ W2,
                                                        const float* __restrict__ b2,
                                                        float* __restrict__ out) {
    __shared__ float p[128];
    __shared__ float hid[40];
    int g = blockIdx.x, t = threadIdx.x;
    int lo = lower_bound_i(batch, NN, g);
    int hi = lower_bound_i(batch, NN, g + 1);
    float s = 0.f;
    int w = t >> 1, odd = t & 1;
    for (int i = lo; i < hi; ++i) {
        u32 v = h3u[(size_t)i * 64 + w];
        s += odd ? b2f_hi(v) : b2f_lo(v);
    }
    p[t] = s / fmaxf((float)(hi - lo), 1.f);
    __syncthreads();
    if (t < 40) {
        float v = b1[t];
        for (int k = 0; k < 128; ++k) v += p[k] * W1[k * 40 + t];
        hid[t] = v;
    }
    __syncthreads();
    if (t < 10) {
        float v = b2[t];
        for (int j = 0; j < 40; ++j) v += hid[j] * W2[j * 10 + t];
        out[g * 10 + t] = v;
    }
}

// ---------------- launch ----------------

extern "C" void kernel_launch(void* const* d_in, const int* in_sizes, int n_in,
                              void* d_out, int out_size, void* d_ws, size_t ws_size,
                              hipStream_t stream) {
    const float* x   = (const float*)d_in[0];
    const int* ei    = (const int*)d_in[1];
    const int* batch = (const int*)d_in[2];
    const float* Wr1 = (const float*)d_in[3];
    const float* br1 = (const float*)d_in[4];
    const float* Wo1 = (const float*)d_in[5];
    const float* Wr2 = (const float*)d_in[6];
    const float* br2 = (const float*)d_in[7];
    const float* Wo2 = (const float*)d_in[8];
    const float* Wr3 = (const float*)d_in[9];
    const float* br3 = (const float*)d_in[10];
    const float* Wo3 = (const float*)d_in[11];
    const float* W1  = (const float*)d_in[12];
    const float* b1  = (const float*)d_in[13];
    const float* W2  = (const float*)d_in[14];
    const float* b2  = (const float*)d_in[15];
    float* out = (float*)d_out;

    char* ws = (char*)d_ws;
    size_t off = 0;
    auto alloc = [&](size_t bytes) {
        void* p = ws + off;
        off += (bytes + 255) & ~(size_t)255;
        return p;
    };
    int* ofs   = (int*)alloc((NN + 1) * sizeof(int));
    int* bcnt  = (int*)alloc(256 * sizeof(int));
    int* srcl  = (int*)alloc((size_t)EE * sizeof(int));
    u16* ax    = (u16*)alloc((size_t)NN * 256 * 2);   // cols 0-127 agg, 128-255 x_bf
    u16* ah1   = (u16*)alloc((size_t)NN * 256 * 2);
    u16* h2    = (u16*)alloc((size_t)NN * 256 * 2);
    u16* t3o3  = (u16*)alloc((size_t)NN * 256 * 2);   // cols 0-127 t3, 128-255 o3
    u16* h3    = (u16*)alloc((size_t)NN * 128 * 2);   // bf16
    u16* BT1   = (u16*)alloc(128 * 256 * 2);
    u16* BT2   = (u16*)alloc(256 * 256 * 2);
    u16* BT3   = (u16*)alloc(256 * 256 * 2);
    float* bias3 = (float*)alloc(256 * sizeof(float));
    // pairs (12.85 MB) overlays h2 (25.6 MB): pairs lifetime ends at bfill,
    // h2 first written at gemm2.
    u32* pairs = (u32*)h2;

    // CSR by dst
    hipMemsetAsync(bcnt, 0, 256 * sizeof(int), stream);
    bscatter_kernel<<<(EE + 4095) / 4096, 256, 0, stream>>>(ei, bcnt, pairs);
    bfill_kernel<<<NB, 256, 0, stream>>>(pairs, bcnt, ofs, srcl);

    // x conversion + weight prep (merged)
    prep_kernel<<<NN * 32 / 256 + 256, 256, 0, stream>>>(
        x, ax, Wr1, Wo1, Wr2, Wo2, Wr3, Wo3, br3, BT1, BT2, BT3, bias3);

    // conv1
    pull_bf_kernel<<<NN * 64 / 256, 256, 0, stream>>>((const u32*)ax + 64, ofs, srcl, (u32*)ax);
    gemm_bf_kernel<<<dim3(1, 391), 256, 0, stream>>>(ax, BT1, br1, ah1, 256, 128, 1);
    // conv2
    pull_bf_kernel<<<NN * 64 / 256, 256, 0, stream>>>((const u32*)ah1 + 64, ofs, srcl, (u32*)ah1);
    gemm_bf_kernel<<<dim3(2, 391), 256, 0, stream>>>(ah1, BT2, br2, h2, 256, 0, 1);
    // conv3: [t3|o3] = h2 @ [Wr3|Wo3] (+ [0|br3])
    gemm_bf_kernel<<<dim3(2, 391), 256, 0, stream>>>(h2, BT3, bias3, t3o3, 256, 0, 0);
    // h3 = agg(t3) + o3  (bf16)
    pull3_kernel<<<NN * 64 / 256, 256, 0, stream>>>((const u32*)t3o3, ofs, srcl, (u32*)h3);

    // fused mean pool + head
    pool_head_kernel<<<GG, 128, 0, stream>>>((const u32*)h3, batch, W1, b1, W2, b2, out);
}

// Round 6
// 379.371 us; speedup vs baseline: 2.7942x; 1.0442x over previous
//
#include <hip/hip_runtime.h>
#include <hip/hip_bf16.h>
#include <cstddef>

#define NN 50000
#define EE 1600000
#define GG 512
#define NB 196        // ceil(NN/256) buckets of 256 nodes
#define BSTRIDE 16384 // fixed pairs-region capacity per bucket (max span ~8600)
#define BCAP 10240    // LDS staging per bucket
#define XBLKS 6250    // NN*32/256 x-convert blocks
#define SCBLKS 391    // (EE+4095)/4096 bscatter blocks

typedef unsigned int u32;
typedef unsigned short u16;
typedef __attribute__((ext_vector_type(8))) short frag_ab;   // 8 bf16 = 4 VGPRs
typedef __attribute__((ext_vector_type(4))) float frag_cd;   // 4 fp32 acc

__device__ __forceinline__ void gl_lds16(const void* g, void* l) {
    __builtin_amdgcn_global_load_lds(
        (const __attribute__((address_space(1))) u32*)g,
        (__attribute__((address_space(3))) u32*)l, 16, 0, 0);
}
__device__ __forceinline__ float b2f_lo(u32 v) { return __uint_as_float(v << 16); }
__device__ __forceinline__ float b2f_hi(u32 v) { return __uint_as_float(v & 0xffff0000u); }
__device__ __forceinline__ u16 f2b(float x) {
    __hip_bfloat16 h = __float2bfloat16(x);
    return *(u16*)&h;
}
__device__ __forceinline__ u32 pack2(float lo, float hi) {
    return ((u32)f2b(hi) << 16) | f2b(lo);
}
// packed accumulate: acc += {lo(v), hi(v)} (compiler can emit v_pk_add_f32)
__device__ __forceinline__ void acc2(float2& a, u32 v) {
    a.x += b2f_lo(v);
    a.y += b2f_hi(v);
}

// ---------------- fused: edge bucket-scatter + x->bf16 + weight prep ----------------

__global__ __launch_bounds__(256) void bscatter_prep_kernel(
    const int* __restrict__ ei, int* __restrict__ bcnt, u32* __restrict__ pairs,
    const float* __restrict__ x, u16* __restrict__ ax,
    const float* __restrict__ Wr1, const float* __restrict__ Wo1,
    const float* __restrict__ Wr2, const float* __restrict__ Wo2,
    const float* __restrict__ Wr3, const float* __restrict__ Wo3,
    const float* __restrict__ br3,
    u16* __restrict__ BT1, u16* __restrict__ BT2, u16* __restrict__ BT3,
    float* __restrict__ bias3) {
    __shared__ int lcnt[NB];
    __shared__ int lbase[NB];
    __shared__ unsigned short lpos[4096];
    int bid = blockIdx.x, t = threadIdx.x;
    if (bid < SCBLKS) {
        int e0 = bid * 4096;
        for (int i = t; i < NB; i += 256) lcnt[i] = 0;
        __syncthreads();
#pragma unroll
        for (int i = 0; i < 16; ++i) {
            int e = e0 + i * 256 + t;
            if (e < EE) {
                int b = ei[EE + e] >> 8;
                lpos[i * 256 + t] = (unsigned short)atomicAdd(&lcnt[b], 1);
            }
        }
        __syncthreads();
        for (int i = t; i < NB; i += 256) lbase[i] = atomicAdd(&bcnt[i], lcnt[i]);
        __syncthreads();
#pragma unroll
        for (int i = 0; i < 16; ++i) {
            int e = e0 + i * 256 + t;
            if (e < EE) {
                int src = ei[e], dst = ei[EE + e];
                int b = dst >> 8;
                int pos = lbase[b] + (int)lpos[i * 256 + t];
                pairs[(size_t)b * BSTRIDE + pos] = ((u32)src << 8) | (u32)(dst & 255);
            }
        }
    } else if (bid < SCBLKS + XBLKS) {
        int idx = (bid - SCBLKS) * 256 + t;
        int row = idx >> 5, q = idx & 31;
        float4 v = *(const float4*)(x + (size_t)row * 128 + q * 4);
        *(u32*)(ax + (size_t)row * 256 + 128 + q * 4) = pack2(v.x, v.y);
        *(u32*)(ax + (size_t)row * 256 + 128 + q * 4 + 2) = pack2(v.z, v.w);
    } else {
        int m = bid - SCBLKS - XBLKS;   // 0..255 output col
        int k = t;                       // reduction idx
        BT2[m * 256 + k] = f2b(k < 128 ? Wr2[k * 256 + m] : Wo2[(k - 128) * 256 + m]);
        BT3[m * 256 + k] = f2b(m < 128 ? Wr3[k * 128 + m] : Wo3[k * 128 + (m - 128)]);
        if (m < 128)
            BT1[m * 256 + k] = f2b(k < 128 ? Wr1[k * 128 + m] : Wo1[(k - 128) * 128 + m]);
        if (k == 0) bias3[m] = (m < 128) ? 0.f : br3[m - 128];
    }
}

// ---------------- CSR pass 2 ----------------

__global__ __launch_bounds__(256) void bfill_kernel(const u32* __restrict__ pairs,
                                                    const int* __restrict__ bcnt,
                                                    int* __restrict__ ofs,
                                                    int* __restrict__ srcl) {
    __shared__ int sc[256];
    __shared__ int cnts[256];
    __shared__ int lcnt[256];
    __shared__ int lcur[256];
    __shared__ int lbuf[BCAP];
    int b = blockIdx.x, t = threadIdx.x;
    int c = (t < NB) ? bcnt[t] : 0;
    cnts[t] = c;
    sc[t] = c;
    lcnt[t] = 0;
    __syncthreads();
    for (int off = 1; off < 256; off <<= 1) {
        int v = (t >= off) ? sc[t - off] : 0;
        __syncthreads();
        sc[t] += v;
        __syncthreads();
    }
    int base = sc[b] - cnts[b];
    int span = cnts[b];
    const u32* pp = pairs + (size_t)b * BSTRIDE;
    for (int j = t; j < span; j += 256) atomicAdd(&lcnt[pp[j] & 255u], 1);
    __syncthreads();
    int nc = lcnt[t];
    sc[t] = nc;
    __syncthreads();
    for (int off = 1; off < 256; off <<= 1) {
        int v = (t >= off) ? sc[t - off] : 0;
        __syncthreads();
        sc[t] += v;
        __syncthreads();
    }
    int excl = sc[t] - nc;
    int node = b * 256 + t;
    if (node < NN) ofs[node] = base + excl;
    if (b == NB - 1 && t == 0) ofs[NN] = EE;
    lcur[t] = excl;
    __syncthreads();
    for (int j = t; j < span; j += 256) {
        u32 p = pp[j];
        int pos = atomicAdd(&lcur[p & 255u], 1);
        int src = (int)(p >> 8);
        if (pos < BCAP) lbuf[pos] = src;
        else srcl[base + pos] = src;
    }
    __syncthreads();
    int lim = span < BCAP ? span : BCAP;
    for (int j = t; j < lim; j += 256) srcl[base + j] = lbuf[j];
}

// ---------------- bf16 pull, wide-load, 16-edge unroll ----------------
// One wave per node. q=lane>>4: edge slot; l=lane&15: channel group (8 ch, dwordx4).

__global__ __launch_bounds__(256) void pull_bf_kernel(const u32* __restrict__ Xu,
                                                      const int* __restrict__ ofs,
                                                      const int* __restrict__ srcl,
                                                      u32* __restrict__ outu) {
    int node = (blockIdx.x * 256 + threadIdx.x) >> 6;
    int lane = threadIdx.x & 63;
    int q = lane >> 4, l = lane & 15;
    int lo = ofs[node], hi = ofs[node + 1];
    float2 a0 = {0.f, 0.f}, a1 = {0.f, 0.f}, a2 = {0.f, 0.f}, a3 = {0.f, 0.f};
    int j = lo;
    for (; j + 15 < hi; j += 16) {
        int s0 = srcl[j + q], s1 = srcl[j + 4 + q];
        int s2 = srcl[j + 8 + q], s3 = srcl[j + 12 + q];
        uint4 v0 = *(const uint4*)(Xu + (size_t)s0 * 128 + l * 4);
        uint4 v1 = *(const uint4*)(Xu + (size_t)s1 * 128 + l * 4);
        uint4 v2 = *(const uint4*)(Xu + (size_t)s2 * 128 + l * 4);
        uint4 v3 = *(const uint4*)(Xu + (size_t)s3 * 128 + l * 4);
        acc2(a0, v0.x); acc2(a1, v0.y); acc2(a2, v0.z); acc2(a3, v0.w);
        acc2(a0, v1.x); acc2(a1, v1.y); acc2(a2, v1.z); acc2(a3, v1.w);
        acc2(a0, v2.x); acc2(a1, v2.y); acc2(a2, v2.z); acc2(a3, v2.w);
        acc2(a0, v3.x); acc2(a1, v3.y); acc2(a2, v3.z); acc2(a3, v3.w);
    }
    for (; j + 3 < hi; j += 4) {
        int s = srcl[j + q];
        uint4 v = *(const uint4*)(Xu + (size_t)s * 128 + l * 4);
        acc2(a0, v.x); acc2(a1, v.y); acc2(a2, v.z); acc2(a3, v.w);
    }
    if (j + q < hi) {
        int s = srcl[j + q];
        uint4 v = *(const uint4*)(Xu + (size_t)s * 128 + l * 4);
        acc2(a0, v.x); acc2(a1, v.y); acc2(a2, v.z); acc2(a3, v.w);
    }
    float acc[8] = {a0.x, a0.y, a1.x, a1.y, a2.x, a2.y, a3.x, a3.y};
#pragma unroll
    for (int i = 0; i < 8; ++i) {
        acc[i] += __shfl_xor(acc[i], 16, 64);
        acc[i] += __shfl_xor(acc[i], 32, 64);
    }
    if (q == 0) {
        uint4 r;
        r.x = pack2(acc[0], acc[1]);
        r.y = pack2(acc[2], acc[3]);
        r.z = pack2(acc[4], acc[5]);
        r.w = pack2(acc[6], acc[7]);
        *(uint4*)(outu + (size_t)node * 128 + l * 4) = r;
    }
}

// pull3+pool: pooled[g] += agg(t3)[node] + o3[node]  (fp32 atomics; head divides)
__global__ __launch_bounds__(256) void pull3_pool_kernel(const u32* __restrict__ Tu,
                                                         const int* __restrict__ ofs,
                                                         const int* __restrict__ srcl,
                                                         const int* __restrict__ batch,
                                                         float* __restrict__ pooled) {
    int node = (blockIdx.x * 256 + threadIdx.x) >> 6;
    int lane = threadIdx.x & 63;
    int q = lane >> 4, l = lane & 15;
    int lo = ofs[node], hi = ofs[node + 1];
    float2 a0 = {0.f, 0.f}, a1 = {0.f, 0.f}, a2 = {0.f, 0.f}, a3 = {0.f, 0.f};
    int j = lo;
    for (; j + 15 < hi; j += 16) {
        int s0 = srcl[j + q], s1 = srcl[j + 4 + q];
        int s2 = srcl[j + 8 + q], s3 = srcl[j + 12 + q];
        uint4 v0 = *(const uint4*)(Tu + (size_t)s0 * 128 + l * 4);
        uint4 v1 = *(const uint4*)(Tu + (size_t)s1 * 128 + l * 4);
        uint4 v2 = *(const uint4*)(Tu + (size_t)s2 * 128 + l * 4);
        uint4 v3 = *(const uint4*)(Tu + (size_t)s3 * 128 + l * 4);
        acc2(a0, v0.x); acc2(a1, v0.y); acc2(a2, v0.z); acc2(a3, v0.w);
        acc2(a0, v1.x); acc2(a1, v1.y); acc2(a2, v1.z); acc2(a3, v1.w);
        acc2(a0, v2.x); acc2(a1, v2.y); acc2(a2, v2.z); acc2(a3, v2.w);
        acc2(a0, v3.x); acc2(a1, v3.y); acc2(a2, v3.z); acc2(a3, v3.w);
    }
    for (; j + 3 < hi; j += 4) {
        int s = srcl[j + q];
        uint4 v = *(const uint4*)(Tu + (size_t)s * 128 + l * 4);
        acc2(a0, v.x); acc2(a1, v.y); acc2(a2, v.z); acc2(a3, v.w);
    }
    if (j + q < hi) {
        int s = srcl[j + q];
        uint4 v = *(const uint4*)(Tu + (size_t)s * 128 + l * 4);
        acc2(a0, v.x); acc2(a1, v.y); acc2(a2, v.z); acc2(a3, v.w);
    }
    float acc[8] = {a0.x, a0.y, a1.x, a1.y, a2.x, a2.y, a3.x, a3.y};
#pragma unroll
    for (int i = 0; i < 8; ++i) {
        acc[i] += __shfl_xor(acc[i], 16, 64);
        acc[i] += __shfl_xor(acc[i], 32, 64);
    }
    // each quad commits its 2 channels: ch = 8*l + 2*q (+1); o3 word = 64 + 4*l + q
    int g = batch[node];
    u32 o = Tu[(size_t)node * 128 + 64 + l * 4 + q];
    float v0 = acc[2 * q] + b2f_lo(o);
    float v1 = acc[2 * q + 1] + b2f_hi(o);
    float* pp = pooled + g * 128 + 8 * l + 2 * q;
    atomicAdd(pp, v0);
    atomicAdd(pp + 1, v1);
}

// ---------------- bf16 MFMA GEMM: C = relu?(A @ BT^T + bias), K=256 ----------------

__global__ __launch_bounds__(256, 2) void gemm_bf_kernel(
    const u16* __restrict__ A, const u16* __restrict__ BT,
    const float* __restrict__ bias, u16* __restrict__ C,
    int ldc, int coloff, int relu) {
    __shared__ alignas(16) u16 As[128 * 32];
    __shared__ alignas(16) u16 Bs[128 * 32];
    const int t = threadIdx.x;
    const int lane = t & 63, wid = t >> 6;
    const int quad = lane >> 4, l16 = lane & 15;
    const int wm = wid >> 1, wn = wid & 1;
    const int row0 = blockIdx.y * 128, c0 = blockIdx.x * 128;

    frag_cd acc[4][4];
#pragma unroll
    for (int i = 0; i < 4; ++i)
#pragma unroll
        for (int j = 0; j < 4; ++j) acc[i][j] = (frag_cd)0.f;

    const int ca = t, cb = t + 256;
    const int ra = ca >> 2, oa = (ca & 3) * 8;
    const int rb = cb >> 2, ob = (cb & 3) * 8;
    const int garow = min(row0 + ra, NN - 1);
    const int gbrow = min(row0 + rb, NN - 1);
    const size_t gA1 = (size_t)garow * 256 + oa;
    const size_t gA2 = (size_t)gbrow * 256 + ob;
    const size_t gB1 = (size_t)(c0 + ra) * 256 + oa;
    const size_t gB2 = (size_t)(c0 + rb) * 256 + ob;

    for (int kk = 0; kk < 256; kk += 32) {
        __syncthreads();
        gl_lds16(A + gA1 + kk, &As[ca * 8]);
        gl_lds16(A + gA2 + kk, &As[cb * 8]);
        gl_lds16(BT + gB1 + kk, &Bs[ca * 8]);
        gl_lds16(BT + gB2 + kk, &Bs[cb * 8]);
        __syncthreads();

        frag_ab a[4], b[4];
#pragma unroll
        for (int mt = 0; mt < 4; ++mt)
            a[mt] = *(const frag_ab*)&As[(wm * 64 + mt * 16 + l16) * 32 + quad * 8];
#pragma unroll
        for (int nt = 0; nt < 4; ++nt)
            b[nt] = *(const frag_ab*)&Bs[(wn * 64 + nt * 16 + l16) * 32 + quad * 8];
#pragma unroll
        for (int mt = 0; mt < 4; ++mt)
#pragma unroll
            for (int nt = 0; nt < 4; ++nt)
                acc[mt][nt] = __builtin_amdgcn_mfma_f32_16x16x32_bf16(
                    a[mt], b[nt], acc[mt][nt], 0, 0, 0);
    }

#pragma unroll
    for (int nt = 0; nt < 4; ++nt) {
        int col = c0 + wn * 64 + nt * 16 + l16;
        float bv = bias[col];
#pragma unroll
        for (int mt = 0; mt < 4; ++mt) {
#pragma unroll
            for (int r = 0; r < 4; ++r) {
                int row = row0 + wm * 64 + mt * 16 + quad * 4 + r;
                if (row < NN) {
                    float v = acc[mt][nt][r] + bv;
                    if (relu) v = fmaxf(v, 0.f);
                    C[(size_t)row * ldc + coloff + col] = f2b(v);
                }
            }
        }
    }
}

// ---------------- head: out = (pooled_sum/cnt) @ W1 + b1) @ W2 + b2 ----------------

__device__ inline int lower_bound_i(const int* a, int n, int v) {
    int lo = 0, hi = n;
    while (lo < hi) {
        int m = (lo + hi) >> 1;
        if (a[m] < v) lo = m + 1; else hi = m;
    }
    return lo;
}

__global__ __launch_bounds__(64) void head_kernel(const float* __restrict__ pooled,
                                                  const int* __restrict__ batch,
                                                  const float* __restrict__ W1,
                                                  const float* __restrict__ b1,
                                                  const float* __restrict__ W2,
                                                  const float* __restrict__ b2,
                                                  float* __restrict__ out) {
    __shared__ float p[128];
    __shared__ float hid[40];
    int g = blockIdx.x, t = threadIdx.x;
    int lo = lower_bound_i(batch, NN, g);
    int hi = lower_bound_i(batch, NN, g + 1);
    float inv = 1.f / fmaxf((float)(hi - lo), 1.f);
    p[t] = pooled[g * 128 + t] * inv;
    p[t + 64] = pooled[g * 128 + 64 + t] * inv;
    __syncthreads();
    if (t < 40) {
        float v = b1[t];
        for (int k = 0; k < 128; ++k) v += p[k] * W1[k * 40 + t];
        hid[t] = v;
    }
    __syncthreads();
    if (t < 10) {
        float v = b2[t];
        for (int j = 0; j < 40; ++j) v += hid[j] * W2[j * 10 + t];
        out[g * 10 + t] = v;
    }
}

// ---------------- launch ----------------

extern "C" void kernel_launch(void* const* d_in, const int* in_sizes, int n_in,
                              void* d_out, int out_size, void* d_ws, size_t ws_size,
                              hipStream_t stream) {
    const float* x   = (const float*)d_in[0];
    const int* ei    = (const int*)d_in[1];
    const int* batch = (const int*)d_in[2];
    const float* Wr1 = (const float*)d_in[3];
    const float* br1 = (const float*)d_in[4];
    const float* Wo1 = (const float*)d_in[5];
    const float* Wr2 = (const float*)d_in[6];
    const float* br2 = (const float*)d_in[7];
    const float* Wo2 = (const float*)d_in[8];
    const float* Wr3 = (const float*)d_in[9];
    const float* br3 = (const float*)d_in[10];
    const float* Wo3 = (const float*)d_in[11];
    const float* W1  = (const float*)d_in[12];
    const float* b1  = (const float*)d_in[13];
    const float* W2  = (const float*)d_in[14];
    const float* b2  = (const float*)d_in[15];
    float* out = (float*)d_out;

    char* ws = (char*)d_ws;
    size_t off = 0;
    auto alloc = [&](size_t bytes) {
        void* p = ws + off;
        off += (bytes + 255) & ~(size_t)255;
        return p;
    };
    int* ofs      = (int*)alloc((NN + 1) * sizeof(int));
    int* bcnt     = (int*)alloc(256 * sizeof(int));           // | one memset covers
    float* pooled = (float*)alloc((size_t)GG * 128 * sizeof(float));  // | both (adjacent)
    int* srcl     = (int*)alloc((size_t)EE * sizeof(int));
    u16* ax       = (u16*)alloc((size_t)NN * 256 * 2);   // cols 0-127 agg, 128-255 x_bf
    u16* ah1      = (u16*)alloc((size_t)NN * 256 * 2);
    u16* h2       = (u16*)alloc((size_t)NN * 256 * 2);
    u16* t3o3     = (u16*)alloc((size_t)NN * 256 * 2);   // cols 0-127 t3, 128-255 o3
    u16* BT1      = (u16*)alloc(128 * 256 * 2);
    u16* BT2      = (u16*)alloc(256 * 256 * 2);
    u16* BT3      = (u16*)alloc(256 * 256 * 2);
    float* bias3  = (float*)alloc(256 * sizeof(float));
    // pairs (12.85 MB) overlays h2 (25.6 MB): pairs lifetime ends at bfill,
    // h2 first written at gemm2.
    u32* pairs = (u32*)h2;

    // zero bcnt + pooled in one memset (adjacent allocations)
    hipMemsetAsync(bcnt, 0, 256 * sizeof(int) + (size_t)GG * 128 * sizeof(float), stream);

    // CSR pass 1 + x->bf16 + weight prep (fused, independent block ranges)
    bscatter_prep_kernel<<<SCBLKS + XBLKS + 256, 256, 0, stream>>>(
        ei, bcnt, pairs, x, ax, Wr1, Wo1, Wr2, Wo2, Wr3, Wo3, br3,
        BT1, BT2, BT3, bias3);
    // CSR pass 2
    bfill_kernel<<<NB, 256, 0, stream>>>(pairs, bcnt, ofs, srcl);

    // conv1
    pull_bf_kernel<<<NN * 64 / 256, 256, 0, stream>>>((const u32*)ax + 64, ofs, srcl, (u32*)ax);
    gemm_bf_kernel<<<dim3(1, 391), 256, 0, stream>>>(ax, BT1, br1, ah1, 256, 128, 1);
    // conv2
    pull_bf_kernel<<<NN * 64 / 256, 256, 0, stream>>>((const u32*)ah1 + 64, ofs, srcl, (u32*)ah1);
    gemm_bf_kernel<<<dim3(2, 391), 256, 0, stream>>>(ah1, BT2, br2, h2, 256, 0, 1);
    // conv3: [t3|o3] = h2 @ [Wr3|Wo3] (+ [0|br3])
    gemm_bf_kernel<<<dim3(2, 391), 256, 0, stream>>>(h2, BT3, bias3, t3o3, 256, 0, 0);
    // pooled += agg(t3) + o3  (per-node, fp32 atomics)
    pull3_pool_kernel<<<NN * 64 / 256, 256, 0, stream>>>((const u32*)t3o3, ofs, srcl,
                                                         batch, pooled);
    // head
    head_kernel<<<GG, 64, 0, stream>>>(pooled, batch, W1, b1, W2, b2, out);
}